// Round 1
// baseline (2322.682 us; speedup 1.0000x reference)
//
#include <hip/hip_runtime.h>
#include <math.h>

#define N_NODES 100000
#define N_EDGES 1600000

// ---- ws layout (in floats) ----
#define OFF_DEG    0L
#define OFF_AGG1   100352L                       // 100000 deg, padded
#define OFF_AGG2   (OFF_AGG1 + 6400000L)         // agg1: 100000*64
#define ZERO_FLOATS (OFF_AGG2 + 12800000L)       // agg2: 100000*128 ; zero [0, here)
#define OFF_H      ZERO_FLOATS                   // h: 100000*128 (reused as c1)
#define OFF_WT     (OFF_H + 12800000L)           // 6 transposed weight mats, 8192 each

// dst[o*R + k] = src[k*C + o]   (src is [R rows(k) x C cols(o)])
__global__ void transpose_w(const float* __restrict__ src, float* __restrict__ dst,
                            int R, int C) {
    int i = blockIdx.x * blockDim.x + threadIdx.x;
    if (i >= R * C) return;
    int k = i / C, o = i % C;
    dst[o * R + k] = src[i];
}

// one thread per (edge, channel); 64 channels
__global__ void agg64_deg(const float* __restrict__ x, const int* __restrict__ esrc,
                          const int* __restrict__ edst, float* __restrict__ agg,
                          float* __restrict__ deg) {
    long gid = (long)blockIdx.x * 256 + threadIdx.x;
    int e = (int)(gid >> 6);
    if (e >= N_EDGES) return;
    int c = threadIdx.x & 63;
    int s = esrc[e], d = edst[e];
    atomicAdd(&agg[(long)d * 64 + c], x[(long)s * 64 + c]);
    if (c == 0) atomicAdd(&deg[d], 1.0f);
}

// one thread per (edge, channel); 128 channels
__global__ void agg128(const float* __restrict__ h, const int* __restrict__ esrc,
                       const int* __restrict__ edst, float* __restrict__ agg) {
    long gid = (long)blockIdx.x * 256 + threadIdx.x;
    int e = (int)(gid >> 7);
    if (e >= N_EDGES) return;
    int c = threadIdx.x & 127;
    int s = esrc[e], d = edst[e];
    atomicAdd(&agg[(long)d * 128 + c], h[(long)s * 128 + c]);
}

// h = relu((agg1/deg) @ Wl1 + bl1 + x @ Wr1)   [64 -> 128]
__global__ void dense1(const float* __restrict__ x, const float* __restrict__ agg,
                       const float* __restrict__ deg, const float* __restrict__ wlT,
                       const float* __restrict__ wrT, const float* __restrict__ b,
                       float* __restrict__ h) {
    int i = blockIdx.x * blockDim.x + threadIdx.x;
    if (i >= N_NODES) return;
    float xr[64], ar[64];
    float sc = 1.0f / fmaxf(deg[i], 1.0f);
    {
        const float4* xp = (const float4*)(x + (long)i * 64);
        const float4* ap = (const float4*)(agg + (long)i * 64);
#pragma unroll
        for (int q = 0; q < 16; q++) {
            float4 v = xp[q];
            xr[4*q+0] = v.x; xr[4*q+1] = v.y; xr[4*q+2] = v.z; xr[4*q+3] = v.w;
            float4 a = ap[q];
            ar[4*q+0] = a.x*sc; ar[4*q+1] = a.y*sc; ar[4*q+2] = a.z*sc; ar[4*q+3] = a.w*sc;
        }
    }
    float* hp = h + (long)i * 128;
    for (int og = 0; og < 32; og++) {
        int o0 = og * 4;
        float4 acc = { b[o0], b[o0+1], b[o0+2], b[o0+3] };
        const float* wl0 = wlT + (long)o0 * 64;
        const float* wr0 = wrT + (long)o0 * 64;
#pragma unroll
        for (int k = 0; k < 64; k++) {
            float xv = xr[k], av = ar[k];
            acc.x += av * wl0[k]       + xv * wr0[k];
            acc.y += av * wl0[64 + k]  + xv * wr0[64 + k];
            acc.z += av * wl0[128 + k] + xv * wr0[128 + k];
            acc.w += av * wl0[192 + k] + xv * wr0[192 + k];
        }
        acc.x = fmaxf(acc.x, 0.f); acc.y = fmaxf(acc.y, 0.f);
        acc.z = fmaxf(acc.z, 0.f); acc.w = fmaxf(acc.w, 0.f);
        *(float4*)(hp + o0) = acc;
    }
}

// emb = (agg2/deg) @ Wl2 + bl2      [128 -> 64]
__global__ void dense2a(const float* __restrict__ agg, const float* __restrict__ deg,
                        const float* __restrict__ wT, const float* __restrict__ b,
                        float* __restrict__ out) {
    int i = blockIdx.x * blockDim.x + threadIdx.x;
    if (i >= N_NODES) return;
    float ar[128];
    float sc = 1.0f / fmaxf(deg[i], 1.0f);
    {
        const float4* ap = (const float4*)(agg + (long)i * 128);
#pragma unroll
        for (int q = 0; q < 32; q++) {
            float4 a = ap[q];
            ar[4*q+0] = a.x*sc; ar[4*q+1] = a.y*sc; ar[4*q+2] = a.z*sc; ar[4*q+3] = a.w*sc;
        }
    }
    float* op = out + (long)i * 64;
    for (int og = 0; og < 16; og++) {
        int o0 = og * 4;
        float4 acc = { b[o0], b[o0+1], b[o0+2], b[o0+3] };
        const float* w0 = wT + (long)o0 * 128;
#pragma unroll
        for (int k = 0; k < 128; k++) {
            float av = ar[k];
            acc.x += av * w0[k];
            acc.y += av * w0[128 + k];
            acc.z += av * w0[256 + k];
            acc.w += av * w0[384 + k];
        }
        *(float4*)(op + o0) = acc;
    }
}

// emb += h @ Wr2   [128 -> 64]
__global__ void dense2b(const float* __restrict__ h, const float* __restrict__ wT,
                        float* __restrict__ out) {
    int i = blockIdx.x * blockDim.x + threadIdx.x;
    if (i >= N_NODES) return;
    float hr[128];
    {
        const float4* hp = (const float4*)(h + (long)i * 128);
#pragma unroll
        for (int q = 0; q < 32; q++) {
            float4 a = hp[q];
            hr[4*q+0] = a.x; hr[4*q+1] = a.y; hr[4*q+2] = a.z; hr[4*q+3] = a.w;
        }
    }
    float* op = out + (long)i * 64;
    for (int og = 0; og < 16; og++) {
        int o0 = og * 4;
        float4 acc = *(float4*)(op + o0);
        const float* w0 = wT + (long)o0 * 128;
#pragma unroll
        for (int k = 0; k < 128; k++) {
            float hv = hr[k];
            acc.x += hv * w0[k];
            acc.y += hv * w0[128 + k];
            acc.z += hv * w0[256 + k];
            acc.w += hv * w0[384 + k];
        }
        *(float4*)(op + o0) = acc;
    }
}

// c1 = relu(emb @ Wc1 + bc1)   [64 -> 128]
__global__ void cls1(const float* __restrict__ emb, const float* __restrict__ wT,
                     const float* __restrict__ b, float* __restrict__ c1) {
    int i = blockIdx.x * blockDim.x + threadIdx.x;
    if (i >= N_NODES) return;
    float er[64];
    {
        const float4* ep = (const float4*)(emb + (long)i * 64);
#pragma unroll
        for (int q = 0; q < 16; q++) {
            float4 v = ep[q];
            er[4*q+0] = v.x; er[4*q+1] = v.y; er[4*q+2] = v.z; er[4*q+3] = v.w;
        }
    }
    float* cp = c1 + (long)i * 128;
    for (int og = 0; og < 32; og++) {
        int o0 = og * 4;
        float4 acc = { b[o0], b[o0+1], b[o0+2], b[o0+3] };
        const float* w0 = wT + (long)o0 * 64;
#pragma unroll
        for (int k = 0; k < 64; k++) {
            float ev = er[k];
            acc.x += ev * w0[k];
            acc.y += ev * w0[64 + k];
            acc.z += ev * w0[128 + k];
            acc.w += ev * w0[192 + k];
        }
        acc.x = fmaxf(acc.x, 0.f); acc.y = fmaxf(acc.y, 0.f);
        acc.z = fmaxf(acc.z, 0.f); acc.w = fmaxf(acc.w, 0.f);
        *(float4*)(cp + o0) = acc;
    }
}

// c2 = relu(c1 @ Wc2 + bc2) [128->64]; p = sigmoid(c2 . Wc3 + bc3)
__global__ void cls2(const float* __restrict__ c1, const float* __restrict__ wT,
                     const float* __restrict__ b2, const float* __restrict__ wc3,
                     const float* __restrict__ bc3, float* __restrict__ probs) {
    int i = blockIdx.x * blockDim.x + threadIdx.x;
    if (i >= N_NODES) return;
    float cr[128];
    {
        const float4* cp = (const float4*)(c1 + (long)i * 128);
#pragma unroll
        for (int q = 0; q < 32; q++) {
            float4 v = cp[q];
            cr[4*q+0] = v.x; cr[4*q+1] = v.y; cr[4*q+2] = v.z; cr[4*q+3] = v.w;
        }
    }
    float p = bc3[0];
    for (int og = 0; og < 16; og++) {
        int o0 = og * 4;
        float4 acc = { b2[o0], b2[o0+1], b2[o0+2], b2[o0+3] };
        const float* w0 = wT + (long)o0 * 128;
#pragma unroll
        for (int k = 0; k < 128; k++) {
            float cv = cr[k];
            acc.x += cv * w0[k];
            acc.y += cv * w0[128 + k];
            acc.z += cv * w0[256 + k];
            acc.w += cv * w0[384 + k];
        }
        p += fmaxf(acc.x, 0.f) * wc3[o0]
           + fmaxf(acc.y, 0.f) * wc3[o0+1]
           + fmaxf(acc.z, 0.f) * wc3[o0+2]
           + fmaxf(acc.w, 0.f) * wc3[o0+3];
    }
    probs[i] = 1.0f / (1.0f + expf(-p));
}

extern "C" void kernel_launch(void* const* d_in, const int* in_sizes, int n_in,
                              void* d_out, int out_size, void* d_ws, size_t ws_size,
                              hipStream_t stream) {
    const float* x   = (const float*)d_in[0];
    const int*   ei  = (const int*)d_in[1];
    const float* Wl1 = (const float*)d_in[2];
    const float* bl1 = (const float*)d_in[3];
    const float* Wr1 = (const float*)d_in[4];
    const float* Wl2 = (const float*)d_in[5];
    const float* bl2 = (const float*)d_in[6];
    const float* Wr2 = (const float*)d_in[7];
    const float* Wc1 = (const float*)d_in[8];
    const float* bc1 = (const float*)d_in[9];
    const float* Wc2 = (const float*)d_in[10];
    const float* bc2 = (const float*)d_in[11];
    const float* Wc3 = (const float*)d_in[12];
    const float* bc3 = (const float*)d_in[13];

    float* out = (float*)d_out;
    float* ws  = (float*)d_ws;

    float* deg   = ws + OFF_DEG;
    float* agg1  = ws + OFF_AGG1;
    float* agg2  = ws + OFF_AGG2;
    float* h     = ws + OFF_H;
    float* wt    = ws + OFF_WT;
    float* wl1T = wt;           float* wr1T = wt + 8192;
    float* wl2T = wt + 16384;   float* wr2T = wt + 24576;
    float* wc1T = wt + 32768;   float* wc2T = wt + 40960;
    float* c1    = h;                     // reuse h region after dense2b
    float* emb   = out;                   // [100000 x 64]
    float* probs = out + 6400000L;        // [100000]

    const int* esrc = ei;
    const int* edst = ei + N_EDGES;

    hipMemsetAsync(ws, 0, ZERO_FLOATS * sizeof(float), stream);

    transpose_w<<<32, 256, 0, stream>>>(Wl1, wl1T, 64, 128);
    transpose_w<<<32, 256, 0, stream>>>(Wr1, wr1T, 64, 128);
    transpose_w<<<32, 256, 0, stream>>>(Wl2, wl2T, 128, 64);
    transpose_w<<<32, 256, 0, stream>>>(Wr2, wr2T, 128, 64);
    transpose_w<<<32, 256, 0, stream>>>(Wc1, wc1T, 64, 128);
    transpose_w<<<32, 256, 0, stream>>>(Wc2, wc2T, 128, 64);

    agg64_deg<<<400000, 256, 0, stream>>>(x, esrc, edst, agg1, deg);

    int nb = (N_NODES + 255) / 256;
    dense1<<<nb, 256, 0, stream>>>(x, agg1, deg, wl1T, wr1T, bl1, h);

    agg128<<<800000, 256, 0, stream>>>(h, esrc, edst, agg2);

    dense2a<<<nb, 256, 0, stream>>>(agg2, deg, wl2T, bl2, emb);
    dense2b<<<nb, 256, 0, stream>>>(h, wr2T, emb);

    cls1<<<nb, 256, 0, stream>>>(emb, wc1T, bc1, c1);
    cls2<<<nb, 256, 0, stream>>>(c1, wc2T, bc2, Wc3, bc3, probs);
}

// Round 2
// 1531.439 us; speedup vs baseline: 1.5167x; 1.5167x over previous
//
#include <hip/hip_runtime.h>
#include <math.h>

#define N_NODES 100000
#define N_EDGES 1600000
#define NPAD    100352          // nodes padded to 98*1024

// ---------- ws layout ----------
// ints:   deg_cursor[NPAD] | off[NPAD] | bsum[128] | bpre[128] | bucket[E]
// floats: agg1m/u[6.4M] | t2[6.4M] | h/c1[12.8M] | wT[6*8192]

// dst[o*R + k] = src[k*C + o]
__global__ void transpose_w(const float* __restrict__ src, float* __restrict__ dst,
                            int R, int C) {
    int i = blockIdx.x * blockDim.x + threadIdx.x;
    if (i >= R * C) return;
    int k = i / C, o = i % C;
    dst[o * R + k] = src[i];
}

__global__ void hist_kernel(const int* __restrict__ edst, int* __restrict__ deg) {
    int e = blockIdx.x * 256 + threadIdx.x;   // grid exact: 6250*256 = 1.6M
    atomicAdd(&deg[edst[e]], 1);
}

// 98 blocks x 1024 threads, exact cover of NPAD
__global__ void scan_block(const int* __restrict__ deg, int* __restrict__ off,
                           int* __restrict__ bsum) {
    __shared__ int s[1024];
    int t = threadIdx.x;
    int i = blockIdx.x * 1024 + t;
    int v = deg[i];
    s[t] = v;
    __syncthreads();
    for (int st = 1; st < 1024; st <<= 1) {
        int a = (t >= st) ? s[t - st] : 0;
        __syncthreads();
        s[t] += a;
        __syncthreads();
    }
    off[i] = s[t] - v;                 // exclusive within block
    if (t == 1023) bsum[blockIdx.x] = s[t];
}

__global__ void scan_tops(const int* __restrict__ bsum, int* __restrict__ bpre) {
    if (threadIdx.x == 0) {
        int r = 0;
        for (int b = 0; b < 98; b++) { bpre[b] = r; r += bsum[b]; }
    }
}

__global__ void scan_add(int* __restrict__ off, int* __restrict__ cursor,
                         const int* __restrict__ bpre) {
    int i = blockIdx.x * 1024 + threadIdx.x;
    int v = off[i] + bpre[blockIdx.x];
    off[i] = v;
    cursor[i] = v;                     // cursor starts at node's base offset
}

__global__ void scatter_kernel(const int* __restrict__ esrc, const int* __restrict__ edst,
                               int* __restrict__ cursor, int* __restrict__ bucket) {
    int e = blockIdx.x * 256 + threadIdx.x;   // grid exact
    int d = edst[e];
    int slot = atomicAdd(&cursor[d], 1);
    bucket[slot] = esrc[e];
}

// one wave per node; lane = channel (64). out = mean(y[src]) (+ add)
__global__ void gather_mean64(const float* __restrict__ y, const int* __restrict__ off,
                              const int* __restrict__ bucket, const float* __restrict__ add,
                              float* __restrict__ out) {
    int node = __builtin_amdgcn_readfirstlane(blockIdx.x * 4 + (threadIdx.x >> 6));
    if (node >= N_NODES) return;
    int c = threadIdx.x & 63;
    int e0 = off[node], e1 = off[node + 1];
    float a0 = 0.f, a1 = 0.f;
    int e = e0;
    for (; e + 2 <= e1; e += 2) {
        int s0 = bucket[e], s1 = bucket[e + 1];
        a0 += y[(long)s0 * 64 + c];
        a1 += y[(long)s1 * 64 + c];
    }
    if (e < e1) a0 += y[(long)bucket[e] * 64 + c];
    float sc = 1.0f / fmaxf((float)(e1 - e0), 1.0f);
    float r = (a0 + a1) * sc;
    if (add) r += add[(long)node * 64 + c];
    out[(long)node * 64 + c] = r;
}

// h = relu(agg@Wl1 + bl1 + x@Wr1)  [64 -> 128]; wave w of 4 handles outputs [w*32, w*32+32)
__global__ void dense1(const float* __restrict__ x, const float* __restrict__ agg,
                       const float* __restrict__ wlT, const float* __restrict__ wrT,
                       const float* __restrict__ bl, float* __restrict__ h) {
    int lane = threadIdx.x & 63;
    int node = blockIdx.x * 64 + lane;
    int o0 = __builtin_amdgcn_readfirstlane((threadIdx.x >> 6) * 32);
    if (node >= N_NODES) return;
    float xr[64], ar[64];
    {
        const float4* xp = (const float4*)(x + (long)node * 64);
        const float4* ap = (const float4*)(agg + (long)node * 64);
#pragma unroll
        for (int q = 0; q < 16; q++) {
            float4 v = xp[q];
            xr[4*q] = v.x; xr[4*q+1] = v.y; xr[4*q+2] = v.z; xr[4*q+3] = v.w;
            float4 a = ap[q];
            ar[4*q] = a.x; ar[4*q+1] = a.y; ar[4*q+2] = a.z; ar[4*q+3] = a.w;
        }
    }
    float* hrow = h + (long)node * 128;
    for (int o = 0; o < 32; o++) {
        const float4* wl4 = (const float4*)(wlT + (long)(o0 + o) * 64);
        const float4* wr4 = (const float4*)(wrT + (long)(o0 + o) * 64);
        float a = bl[o0 + o];
#pragma unroll
        for (int q = 0; q < 16; q++) {
            float4 wl = wl4[q], wr = wr4[q];
            a += ar[4*q]*wl.x + ar[4*q+1]*wl.y + ar[4*q+2]*wl.z + ar[4*q+3]*wl.w
               + xr[4*q]*wr.x + xr[4*q+1]*wr.y + xr[4*q+2]*wr.z + xr[4*q+3]*wr.w;
        }
        hrow[o0 + o] = fmaxf(a, 0.f);
    }
}

// t2 = h@Wl2 ; u = h@Wr2 + bl2   [128 -> 64 x2]; wave w handles outputs [w*16, w*16+16)
__global__ void conv2t(const float* __restrict__ h, const float* __restrict__ wlT,
                       const float* __restrict__ wrT, const float* __restrict__ bl,
                       float* __restrict__ t2, float* __restrict__ u) {
    int lane = threadIdx.x & 63;
    int node = blockIdx.x * 64 + lane;
    int o0 = __builtin_amdgcn_readfirstlane((threadIdx.x >> 6) * 16);
    if (node >= N_NODES) return;
    float accL[16], accR[16];
#pragma unroll
    for (int o = 0; o < 16; o++) { accL[o] = 0.f; accR[o] = bl[o0 + o]; }
    const float* hrow = h + (long)node * 128;
    for (int kc = 0; kc < 4; kc++) {
        float hr[32];
        const float4* hp = (const float4*)(hrow + kc * 32);
#pragma unroll
        for (int q = 0; q < 8; q++) {
            float4 v = hp[q];
            hr[4*q] = v.x; hr[4*q+1] = v.y; hr[4*q+2] = v.z; hr[4*q+3] = v.w;
        }
#pragma unroll
        for (int o = 0; o < 16; o++) {
            const float4* wl4 = (const float4*)(wlT + (long)(o0 + o) * 128 + kc * 32);
            const float4* wr4 = (const float4*)(wrT + (long)(o0 + o) * 128 + kc * 32);
            float aL = 0.f, aR = 0.f;
#pragma unroll
            for (int q = 0; q < 8; q++) {
                float4 wl = wl4[q], wr = wr4[q];
                aL += hr[4*q]*wl.x + hr[4*q+1]*wl.y + hr[4*q+2]*wl.z + hr[4*q+3]*wl.w;
                aR += hr[4*q]*wr.x + hr[4*q+1]*wr.y + hr[4*q+2]*wr.z + hr[4*q+3]*wr.w;
            }
            accL[o] += aL; accR[o] += aR;
        }
    }
#pragma unroll
    for (int o = 0; o < 16; o++) {
        t2[(long)node * 64 + o0 + o] = accL[o];
        u[(long)node * 64 + o0 + o]  = accR[o];
    }
}

// c1 = relu(emb@Wc1 + bc1)  [64 -> 128]
__global__ void cls1(const float* __restrict__ emb, const float* __restrict__ wT,
                     const float* __restrict__ b, float* __restrict__ c1) {
    int lane = threadIdx.x & 63;
    int node = blockIdx.x * 64 + lane;
    int o0 = __builtin_amdgcn_readfirstlane((threadIdx.x >> 6) * 32);
    if (node >= N_NODES) return;
    float er[64];
    {
        const float4* ep = (const float4*)(emb + (long)node * 64);
#pragma unroll
        for (int q = 0; q < 16; q++) {
            float4 v = ep[q];
            er[4*q] = v.x; er[4*q+1] = v.y; er[4*q+2] = v.z; er[4*q+3] = v.w;
        }
    }
    float* crow = c1 + (long)node * 128;
    for (int o = 0; o < 32; o++) {
        const float4* w4 = (const float4*)(wT + (long)(o0 + o) * 64);
        float a = b[o0 + o];
#pragma unroll
        for (int q = 0; q < 16; q++) {
            float4 w = w4[q];
            a += er[4*q]*w.x + er[4*q+1]*w.y + er[4*q+2]*w.z + er[4*q+3]*w.w;
        }
        crow[o0 + o] = fmaxf(a, 0.f);
    }
}

// c2 = relu(c1@Wc2 + bc2) [128->64]; p = sigmoid(c2 . wc3 + bc3)
__global__ void cls2(const float* __restrict__ c1, const float* __restrict__ wT,
                     const float* __restrict__ b2, const float* __restrict__ wc3,
                     const float* __restrict__ bc3, float* __restrict__ probs) {
    __shared__ float psum[4][64];
    int lane = threadIdx.x & 63;
    int wv = threadIdx.x >> 6;
    int node = blockIdx.x * 64 + lane;
    int nclamp = node < N_NODES ? node : (N_NODES - 1);
    int o0 = __builtin_amdgcn_readfirstlane(wv * 16);
    float acc[16];
#pragma unroll
    for (int o = 0; o < 16; o++) acc[o] = b2[o0 + o];
    const float* crow = c1 + (long)nclamp * 128;
    for (int kc = 0; kc < 4; kc++) {
        float cr[32];
        const float4* cp = (const float4*)(crow + kc * 32);
#pragma unroll
        for (int q = 0; q < 8; q++) {
            float4 v = cp[q];
            cr[4*q] = v.x; cr[4*q+1] = v.y; cr[4*q+2] = v.z; cr[4*q+3] = v.w;
        }
#pragma unroll
        for (int o = 0; o < 16; o++) {
            const float4* w4 = (const float4*)(wT + (long)(o0 + o) * 128 + kc * 32);
            float a = 0.f;
#pragma unroll
            for (int q = 0; q < 8; q++) {
                float4 w = w4[q];
                a += cr[4*q]*w.x + cr[4*q+1]*w.y + cr[4*q+2]*w.z + cr[4*q+3]*w.w;
            }
            acc[o] += a;
        }
    }
    float p = 0.f;
#pragma unroll
    for (int o = 0; o < 16; o++) p += fmaxf(acc[o], 0.f) * wc3[o0 + o];
    psum[wv][lane] = p;
    __syncthreads();
    if (wv == 0 && node < N_NODES) {
        float tot = psum[0][lane] + psum[1][lane] + psum[2][lane] + psum[3][lane] + bc3[0];
        probs[node] = 1.0f / (1.0f + expf(-tot));
    }
}

extern "C" void kernel_launch(void* const* d_in, const int* in_sizes, int n_in,
                              void* d_out, int out_size, void* d_ws, size_t ws_size,
                              hipStream_t stream) {
    const float* x   = (const float*)d_in[0];
    const int*   ei  = (const int*)d_in[1];
    const float* Wl1 = (const float*)d_in[2];
    const float* bl1 = (const float*)d_in[3];
    const float* Wr1 = (const float*)d_in[4];
    const float* Wl2 = (const float*)d_in[5];
    const float* bl2 = (const float*)d_in[6];
    const float* Wr2 = (const float*)d_in[7];
    const float* Wc1 = (const float*)d_in[8];
    const float* bc1 = (const float*)d_in[9];
    const float* Wc2 = (const float*)d_in[10];
    const float* bc2 = (const float*)d_in[11];
    const float* Wc3 = (const float*)d_in[12];
    const float* bc3 = (const float*)d_in[13];

    float* out = (float*)d_out;

    int* iw         = (int*)d_ws;
    int* deg_cursor = iw;                 // NPAD
    int* off        = iw + NPAD;          // NPAD
    int* bsum       = iw + 2 * NPAD;      // 128
    int* bpre       = iw + 2 * NPAD + 128;
    int* bucket     = iw + 2 * NPAD + 256;  // N_EDGES

    float* fw    = (float*)d_ws + (2 * NPAD + 256 + N_EDGES);
    float* agg1m = fw;                    // 6.4M (reused as u)
    float* u     = fw;
    float* t2    = fw + 6400000L;         // 6.4M
    float* h     = fw + 12800000L;        // 12.8M (reused as c1)
    float* c1    = h;
    float* wts   = fw + 25600000L;        // 6*8192
    float* wl1T = wts;          float* wr1T = wts + 8192;
    float* wl2T = wts + 16384;  float* wr2T = wts + 24576;
    float* wc1T = wts + 32768;  float* wc2T = wts + 40960;

    float* emb   = out;                   // [100000 x 64]
    float* probs = out + 6400000L;        // [100000]

    const int* esrc = ei;
    const int* edst = ei + N_EDGES;

    hipMemsetAsync(deg_cursor, 0, NPAD * sizeof(int), stream);

    transpose_w<<<32, 256, 0, stream>>>(Wl1, wl1T, 64, 128);
    transpose_w<<<32, 256, 0, stream>>>(Wr1, wr1T, 64, 128);
    transpose_w<<<32, 256, 0, stream>>>(Wl2, wl2T, 128, 64);
    transpose_w<<<32, 256, 0, stream>>>(Wr2, wr2T, 128, 64);
    transpose_w<<<32, 256, 0, stream>>>(Wc1, wc1T, 64, 128);
    transpose_w<<<32, 256, 0, stream>>>(Wc2, wc2T, 128, 64);

    hist_kernel<<<6250, 256, 0, stream>>>(edst, deg_cursor);
    scan_block<<<98, 1024, 0, stream>>>(deg_cursor, off, bsum);
    scan_tops<<<1, 64, 0, stream>>>(bsum, bpre);
    scan_add<<<98, 1024, 0, stream>>>(off, deg_cursor, bpre);
    scatter_kernel<<<6250, 256, 0, stream>>>(esrc, edst, deg_cursor, bucket);

    gather_mean64<<<25000, 256, 0, stream>>>(x, off, bucket, nullptr, agg1m);
    dense1<<<1563, 256, 0, stream>>>(x, agg1m, wl1T, wr1T, bl1, h);
    conv2t<<<1563, 256, 0, stream>>>(h, wl2T, wr2T, bl2, t2, u);
    gather_mean64<<<25000, 256, 0, stream>>>(t2, off, bucket, u, emb);
    cls1<<<1563, 256, 0, stream>>>(emb, wc1T, bc1, c1);
    cls2<<<1563, 256, 0, stream>>>(c1, wc2T, bc2, Wc3, bc3, probs);
}

// Round 3
// 1427.488 us; speedup vs baseline: 1.6271x; 1.0728x over previous
//
#include <hip/hip_runtime.h>
#include <math.h>

#define N_NODES 100000
#define N_EDGES 1600000
#define NPAD    100352          // nodes padded to 98*1024

// dst[o*R + k] = src[k*C + o]
__global__ void transpose_w(const float* __restrict__ src, float* __restrict__ dst,
                            int R, int C) {
    int i = blockIdx.x * blockDim.x + threadIdx.x;
    if (i >= R * C) return;
    int k = i / C, o = i % C;
    dst[o * R + k] = src[i];
}

__global__ void hist_kernel(const int* __restrict__ edst, int* __restrict__ deg) {
    int e = blockIdx.x * 256 + threadIdx.x;   // grid exact: 6250*256 = 1.6M
    atomicAdd(&deg[edst[e]], 1);
}

__global__ void scan_block(const int* __restrict__ deg, int* __restrict__ off,
                           int* __restrict__ bsum) {
    __shared__ int s[1024];
    int t = threadIdx.x;
    int i = blockIdx.x * 1024 + t;
    int v = deg[i];
    s[t] = v;
    __syncthreads();
    for (int st = 1; st < 1024; st <<= 1) {
        int a = (t >= st) ? s[t - st] : 0;
        __syncthreads();
        s[t] += a;
        __syncthreads();
    }
    off[i] = s[t] - v;
    if (t == 1023) bsum[blockIdx.x] = s[t];
}

__global__ void scan_tops(const int* __restrict__ bsum, int* __restrict__ bpre) {
    if (threadIdx.x == 0) {
        int r = 0;
        for (int b = 0; b < 98; b++) { bpre[b] = r; r += bsum[b]; }
    }
}

__global__ void scan_add(int* __restrict__ off, int* __restrict__ cursor,
                         const int* __restrict__ bpre) {
    int i = blockIdx.x * 1024 + threadIdx.x;
    int v = off[i] + bpre[blockIdx.x];
    off[i] = v;
    cursor[i] = v;
}

__global__ void scatter_kernel(const int* __restrict__ esrc, const int* __restrict__ edst,
                               int* __restrict__ cursor, int* __restrict__ bucket) {
    int e = blockIdx.x * 256 + threadIdx.x;
    int d = edst[e];
    int slot = atomicAdd(&cursor[d], 1);
    bucket[slot] = esrc[e];
}

// one wave per node; lane = channel (64). out = mean(y[src]) (+ add)
__global__ void gather_mean64(const float* __restrict__ y, const int* __restrict__ off,
                              const int* __restrict__ bucket, const float* __restrict__ add,
                              float* __restrict__ out) {
    int node = __builtin_amdgcn_readfirstlane(blockIdx.x * 4 + (threadIdx.x >> 6));
    if (node >= N_NODES) return;
    int c = threadIdx.x & 63;
    int e0 = off[node], e1 = off[node + 1];
    float a0 = 0.f, a1 = 0.f;
    int e = e0;
    for (; e + 2 <= e1; e += 2) {
        int s0 = bucket[e], s1 = bucket[e + 1];
        a0 += y[(long)s0 * 64 + c];
        a1 += y[(long)s1 * 64 + c];
    }
    if (e < e1) a0 += y[(long)bucket[e] * 64 + c];
    float sc = 1.0f / fmaxf((float)(e1 - e0), 1.0f);
    float r = (a0 + a1) * sc;
    if (add) r += add[(long)node * 64 + c];
    out[(long)node * 64 + c] = r;
}

// h = relu(agg@Wl1 + bl1 + x@Wr1)  [64 -> 128]
// outputs staged col-major (+1 pad) in LDS, then flat coalesced store
__global__ void dense1(const float* __restrict__ x, const float* __restrict__ agg,
                       const float* __restrict__ wlT, const float* __restrict__ wrT,
                       const float* __restrict__ bl, float* __restrict__ h) {
    __shared__ float hout[128 * 65];
    int lane = threadIdx.x & 63;
    int node = blockIdx.x * 64 + lane;
    int o0 = __builtin_amdgcn_readfirstlane((threadIdx.x >> 6) * 32);
    int nclamp = node < N_NODES ? node : (N_NODES - 1);
    float xr[64], ar[64];
    {
        const float4* xp = (const float4*)(x + (long)nclamp * 64);
        const float4* ap = (const float4*)(agg + (long)nclamp * 64);
#pragma unroll
        for (int q = 0; q < 16; q++) {
            float4 v = xp[q];
            xr[4*q] = v.x; xr[4*q+1] = v.y; xr[4*q+2] = v.z; xr[4*q+3] = v.w;
            float4 a = ap[q];
            ar[4*q] = a.x; ar[4*q+1] = a.y; ar[4*q+2] = a.z; ar[4*q+3] = a.w;
        }
    }
    for (int o = 0; o < 32; o++) {
        const float4* wl4 = (const float4*)(wlT + (long)(o0 + o) * 64);
        const float4* wr4 = (const float4*)(wrT + (long)(o0 + o) * 64);
        float a = bl[o0 + o];
#pragma unroll
        for (int q = 0; q < 16; q++) {
            float4 wl = wl4[q], wr = wr4[q];
            a += ar[4*q]*wl.x + ar[4*q+1]*wl.y + ar[4*q+2]*wl.z + ar[4*q+3]*wl.w
               + xr[4*q]*wr.x + xr[4*q+1]*wr.y + xr[4*q+2]*wr.z + xr[4*q+3]*wr.w;
        }
        hout[(o0 + o) * 65 + lane] = fmaxf(a, 0.f);  // banks (o+lane)%32: conflict-free
    }
    __syncthreads();
    long gbase = (long)blockIdx.x * 64 * 128;
    long gmax  = (long)N_NODES * 128;
#pragma unroll
    for (int it = 0; it < 32; it++) {
        int i = it * 256 + threadIdx.x;     // 8192 elems
        int n = i >> 7, c = i & 127;
        long g = gbase + i;
        if (g < gmax) h[g] = hout[c * 65 + n];
    }
}

// t2 = h@Wl2 ; u = h@Wr2 + bl2   [128 -> 64 x2]
__global__ void conv2t(const float* __restrict__ h, const float* __restrict__ wlT,
                       const float* __restrict__ wrT, const float* __restrict__ bl,
                       float* __restrict__ t2, float* __restrict__ u) {
    __shared__ float tout[64 * 65];
    __shared__ float uout[64 * 65];
    int lane = threadIdx.x & 63;
    int node = blockIdx.x * 64 + lane;
    int o0 = __builtin_amdgcn_readfirstlane((threadIdx.x >> 6) * 16);
    int nclamp = node < N_NODES ? node : (N_NODES - 1);
    float accL[16], accR[16];
#pragma unroll
    for (int o = 0; o < 16; o++) { accL[o] = 0.f; accR[o] = bl[o0 + o]; }
    const float* hrow = h + (long)nclamp * 128;
    for (int kc = 0; kc < 4; kc++) {
        float hr[32];
        const float4* hp = (const float4*)(hrow + kc * 32);
#pragma unroll
        for (int q = 0; q < 8; q++) {
            float4 v = hp[q];
            hr[4*q] = v.x; hr[4*q+1] = v.y; hr[4*q+2] = v.z; hr[4*q+3] = v.w;
        }
#pragma unroll
        for (int o = 0; o < 16; o++) {
            const float4* wl4 = (const float4*)(wlT + (long)(o0 + o) * 128 + kc * 32);
            const float4* wr4 = (const float4*)(wrT + (long)(o0 + o) * 128 + kc * 32);
            float aL = 0.f, aR = 0.f;
#pragma unroll
            for (int q = 0; q < 8; q++) {
                float4 wl = wl4[q], wr = wr4[q];
                aL += hr[4*q]*wl.x + hr[4*q+1]*wl.y + hr[4*q+2]*wl.z + hr[4*q+3]*wl.w;
                aR += hr[4*q]*wr.x + hr[4*q+1]*wr.y + hr[4*q+2]*wr.z + hr[4*q+3]*wr.w;
            }
            accL[o] += aL; accR[o] += aR;
        }
    }
#pragma unroll
    for (int o = 0; o < 16; o++) {
        tout[(o0 + o) * 65 + lane] = accL[o];
        uout[(o0 + o) * 65 + lane] = accR[o];
    }
    __syncthreads();
    long gbase = (long)blockIdx.x * 64 * 64;
    long gmax  = (long)N_NODES * 64;
#pragma unroll
    for (int it = 0; it < 16; it++) {
        int i = it * 256 + threadIdx.x;     // 4096 elems
        int n = i >> 6, c = i & 63;
        long g = gbase + i;
        if (g < gmax) {
            t2[g] = tout[c * 65 + n];
            u[g]  = uout[c * 65 + n];
        }
    }
}

// c1 = relu(emb@Wc1 + bc1)  [64 -> 128]
__global__ void cls1(const float* __restrict__ emb, const float* __restrict__ wT,
                     const float* __restrict__ b, float* __restrict__ c1) {
    __shared__ float cout[128 * 65];
    int lane = threadIdx.x & 63;
    int node = blockIdx.x * 64 + lane;
    int o0 = __builtin_amdgcn_readfirstlane((threadIdx.x >> 6) * 32);
    int nclamp = node < N_NODES ? node : (N_NODES - 1);
    float er[64];
    {
        const float4* ep = (const float4*)(emb + (long)nclamp * 64);
#pragma unroll
        for (int q = 0; q < 16; q++) {
            float4 v = ep[q];
            er[4*q] = v.x; er[4*q+1] = v.y; er[4*q+2] = v.z; er[4*q+3] = v.w;
        }
    }
    for (int o = 0; o < 32; o++) {
        const float4* w4 = (const float4*)(wT + (long)(o0 + o) * 64);
        float a = b[o0 + o];
#pragma unroll
        for (int q = 0; q < 16; q++) {
            float4 w = w4[q];
            a += er[4*q]*w.x + er[4*q+1]*w.y + er[4*q+2]*w.z + er[4*q+3]*w.w;
        }
        cout[(o0 + o) * 65 + lane] = fmaxf(a, 0.f);
    }
    __syncthreads();
    long gbase = (long)blockIdx.x * 64 * 128;
    long gmax  = (long)N_NODES * 128;
#pragma unroll
    for (int it = 0; it < 32; it++) {
        int i = it * 256 + threadIdx.x;
        int n = i >> 7, c = i & 127;
        long g = gbase + i;
        if (g < gmax) c1[g] = cout[c * 65 + n];
    }
}

// c2 = relu(c1@Wc2 + bc2) [128->64]; p = sigmoid(c2 . wc3 + bc3)
__global__ void cls2(const float* __restrict__ c1, const float* __restrict__ wT,
                     const float* __restrict__ b2, const float* __restrict__ wc3,
                     const float* __restrict__ bc3, float* __restrict__ probs) {
    __shared__ float psum[4][64];
    int lane = threadIdx.x & 63;
    int wv = threadIdx.x >> 6;
    int node = blockIdx.x * 64 + lane;
    int nclamp = node < N_NODES ? node : (N_NODES - 1);
    int o0 = __builtin_amdgcn_readfirstlane(wv * 16);
    float acc[16];
#pragma unroll
    for (int o = 0; o < 16; o++) acc[o] = b2[o0 + o];
    const float* crow = c1 + (long)nclamp * 128;
    for (int kc = 0; kc < 4; kc++) {
        float cr[32];
        const float4* cp = (const float4*)(crow + kc * 32);
#pragma unroll
        for (int q = 0; q < 8; q++) {
            float4 v = cp[q];
            cr[4*q] = v.x; cr[4*q+1] = v.y; cr[4*q+2] = v.z; cr[4*q+3] = v.w;
        }
#pragma unroll
        for (int o = 0; o < 16; o++) {
            const float4* w4 = (const float4*)(wT + (long)(o0 + o) * 128 + kc * 32);
            float a = 0.f;
#pragma unroll
            for (int q = 0; q < 8; q++) {
                float4 w = w4[q];
                a += cr[4*q]*w.x + cr[4*q+1]*w.y + cr[4*q+2]*w.z + cr[4*q+3]*w.w;
            }
            acc[o] += a;
        }
    }
    float p = 0.f;
#pragma unroll
    for (int o = 0; o < 16; o++) p += fmaxf(acc[o], 0.f) * wc3[o0 + o];
    psum[wv][lane] = p;
    __syncthreads();
    if (wv == 0 && node < N_NODES) {
        float tot = psum[0][lane] + psum[1][lane] + psum[2][lane] + psum[3][lane] + bc3[0];
        probs[node] = 1.0f / (1.0f + expf(-tot));
    }
}

extern "C" void kernel_launch(void* const* d_in, const int* in_sizes, int n_in,
                              void* d_out, int out_size, void* d_ws, size_t ws_size,
                              hipStream_t stream) {
    const float* x   = (const float*)d_in[0];
    const int*   ei  = (const int*)d_in[1];
    const float* Wl1 = (const float*)d_in[2];
    const float* bl1 = (const float*)d_in[3];
    const float* Wr1 = (const float*)d_in[4];
    const float* Wl2 = (const float*)d_in[5];
    const float* bl2 = (const float*)d_in[6];
    const float* Wr2 = (const float*)d_in[7];
    const float* Wc1 = (const float*)d_in[8];
    const float* bc1 = (const float*)d_in[9];
    const float* Wc2 = (const float*)d_in[10];
    const float* bc2 = (const float*)d_in[11];
    const float* Wc3 = (const float*)d_in[12];
    const float* bc3 = (const float*)d_in[13];

    float* out = (float*)d_out;

    int* iw         = (int*)d_ws;
    int* deg_cursor = iw;                 // NPAD
    int* off        = iw + NPAD;          // NPAD
    int* bsum       = iw + 2 * NPAD;      // 128
    int* bpre       = iw + 2 * NPAD + 128;
    int* bucket     = iw + 2 * NPAD + 256;  // N_EDGES

    float* fw    = (float*)d_ws + (2 * NPAD + 256 + N_EDGES);
    float* agg1m = fw;                    // 6.4M (reused as u)
    float* u     = fw;
    float* t2    = fw + 6400000L;         // 6.4M
    float* h     = fw + 12800000L;        // 12.8M (reused as c1)
    float* c1    = h;
    float* wts   = fw + 25600000L;        // 6*8192
    float* wl1T = wts;          float* wr1T = wts + 8192;
    float* wl2T = wts + 16384;  float* wr2T = wts + 24576;
    float* wc1T = wts + 32768;  float* wc2T = wts + 40960;

    float* emb   = out;                   // [100000 x 64]
    float* probs = out + 6400000L;        // [100000]

    const int* esrc = ei;
    const int* edst = ei + N_EDGES;

    hipMemsetAsync(deg_cursor, 0, NPAD * sizeof(int), stream);

    transpose_w<<<32, 256, 0, stream>>>(Wl1, wl1T, 64, 128);
    transpose_w<<<32, 256, 0, stream>>>(Wr1, wr1T, 64, 128);
    transpose_w<<<32, 256, 0, stream>>>(Wl2, wl2T, 128, 64);
    transpose_w<<<32, 256, 0, stream>>>(Wr2, wr2T, 128, 64);
    transpose_w<<<32, 256, 0, stream>>>(Wc1, wc1T, 64, 128);
    transpose_w<<<32, 256, 0, stream>>>(Wc2, wc2T, 128, 64);

    hist_kernel<<<6250, 256, 0, stream>>>(edst, deg_cursor);
    scan_block<<<98, 1024, 0, stream>>>(deg_cursor, off, bsum);
    scan_tops<<<1, 64, 0, stream>>>(bsum, bpre);
    scan_add<<<98, 1024, 0, stream>>>(off, deg_cursor, bpre);
    scatter_kernel<<<6250, 256, 0, stream>>>(esrc, edst, deg_cursor, bucket);

    gather_mean64<<<25000, 256, 0, stream>>>(x, off, bucket, nullptr, agg1m);
    dense1<<<1563, 256, 0, stream>>>(x, agg1m, wl1T, wr1T, bl1, h);
    conv2t<<<1563, 256, 0, stream>>>(h, wl2T, wr2T, bl2, t2, u);
    gather_mean64<<<25000, 256, 0, stream>>>(t2, off, bucket, u, emb);
    cls1<<<1563, 256, 0, stream>>>(emb, wc1T, bc1, c1);
    cls2<<<1563, 256, 0, stream>>>(c1, wc2T, bc2, Wc3, bc3, probs);
}

// Round 4
// 889.991 us; speedup vs baseline: 2.6098x; 1.6039x over previous
//
#include <hip/hip_runtime.h>
#include <math.h>

#define N_NODES 100000
#define N_EDGES 1600000
#define NPAD    100352          // nodes padded to 98*1024

// dst[o*R + k] = src[k*C + o]
__global__ void transpose_w(const float* __restrict__ src, float* __restrict__ dst,
                            int R, int C) {
    int i = blockIdx.x * blockDim.x + threadIdx.x;
    if (i >= R * C) return;
    int k = i / C, o = i % C;
    dst[o * R + k] = src[i];
}

__global__ void hist_kernel(const int* __restrict__ edst, int* __restrict__ deg) {
    int e = blockIdx.x * 256 + threadIdx.x;   // grid exact: 6250*256 = 1.6M
    atomicAdd(&deg[edst[e]], 1);
}

__global__ void scan_block(const int* __restrict__ deg, int* __restrict__ off,
                           int* __restrict__ bsum) {
    __shared__ int s[1024];
    int t = threadIdx.x;
    int i = blockIdx.x * 1024 + t;
    int v = deg[i];
    s[t] = v;
    __syncthreads();
    for (int st = 1; st < 1024; st <<= 1) {
        int a = (t >= st) ? s[t - st] : 0;
        __syncthreads();
        s[t] += a;
        __syncthreads();
    }
    off[i] = s[t] - v;
    if (t == 1023) bsum[blockIdx.x] = s[t];
}

__global__ void scan_tops(const int* __restrict__ bsum, int* __restrict__ bpre) {
    if (threadIdx.x == 0) {
        int r = 0;
        for (int b = 0; b < 98; b++) { bpre[b] = r; r += bsum[b]; }
    }
}

__global__ void scan_add(int* __restrict__ off, int* __restrict__ cursor,
                         const int* __restrict__ bpre) {
    int i = blockIdx.x * 1024 + threadIdx.x;
    int v = off[i] + bpre[blockIdx.x];
    off[i] = v;
    cursor[i] = v;
}

__global__ void scatter_kernel(const int* __restrict__ esrc, const int* __restrict__ edst,
                               int* __restrict__ cursor, int* __restrict__ bucket) {
    int e = blockIdx.x * 256 + threadIdx.x;
    int d = edst[e];
    int slot = atomicAdd(&cursor[d], 1);
    bucket[slot] = esrc[e];
}

// one wave per node; lane = channel (64). out = mean(y[src]) (+ add)
__global__ void gather_mean64(const float* __restrict__ y, const int* __restrict__ off,
                              const int* __restrict__ bucket, const float* __restrict__ add,
                              float* __restrict__ out) {
    int node = __builtin_amdgcn_readfirstlane(blockIdx.x * 4 + (threadIdx.x >> 6));
    if (node >= N_NODES) return;
    int c = threadIdx.x & 63;
    int e0 = off[node], e1 = off[node + 1];
    float a0 = 0.f, a1 = 0.f;
    int e = e0;
    for (; e + 2 <= e1; e += 2) {
        int s0 = bucket[e], s1 = bucket[e + 1];
        a0 += y[(long)s0 * 64 + c];
        a1 += y[(long)s1 * 64 + c];
    }
    if (e < e1) a0 += y[(long)bucket[e] * 64 + c];
    float sc = 1.0f / fmaxf((float)(e1 - e0), 1.0f);
    float r = (a0 + a1) * sc;
    if (add) r += add[(long)node * 64 + c];
    out[(long)node * 64 + c] = r;
}

// h = relu(agg@Wl1 + bl1 + x@Wr1)  [64 -> 128]
// LDS-tiled: coalesced tile load, register k-chunks, col-major output staging.
__global__ __launch_bounds__(256, 4) void dense1(
        const float* __restrict__ x, const float* __restrict__ agg,
        const float* __restrict__ wlT, const float* __restrict__ wrT,
        const float* __restrict__ bl, float* __restrict__ h) {
    __shared__ float smem[2 * 64 * 68];   // sx|sa (17.4KB each); aliased by hout[128*65]
    float* sx = smem;
    float* sa = smem + 64 * 68;
    int t = threadIdx.x;
    int lane = t & 63;
    int o0 = __builtin_amdgcn_readfirstlane((t >> 6) * 32);

    long base = (long)blockIdx.x * 64 * 64;
    long maxe = (long)N_NODES * 64 - 4;
#pragma unroll
    for (int it = 0; it < 4; it++) {
        int f4 = it * 256 + t;                    // 0..1023
        int n = f4 >> 4, k4 = (f4 & 15) * 4;
        long g = base + (long)f4 * 4;
        if (g > maxe) g = maxe;
        float4 xv = *(const float4*)(x + g);
        float4 av = *(const float4*)(agg + g);
        *(float4*)(sx + n * 68 + k4) = xv;
        *(float4*)(sa + n * 68 + k4) = av;
    }
    __syncthreads();

    float acc[32];
#pragma unroll
    for (int o = 0; o < 32; o++) acc[o] = bl[o0 + o];
    const float* xrow = sx + lane * 68;
    const float* arow = sa + lane * 68;
#pragma unroll
    for (int kc = 0; kc < 4; kc++) {
        float xr[16], ar[16];
#pragma unroll
        for (int q = 0; q < 4; q++) {
            float4 v = *(const float4*)(xrow + kc * 16 + q * 4);
            xr[4*q] = v.x; xr[4*q+1] = v.y; xr[4*q+2] = v.z; xr[4*q+3] = v.w;
            float4 a = *(const float4*)(arow + kc * 16 + q * 4);
            ar[4*q] = a.x; ar[4*q+1] = a.y; ar[4*q+2] = a.z; ar[4*q+3] = a.w;
        }
#pragma unroll
        for (int o = 0; o < 32; o++) {
            const float4* wl4 = (const float4*)(wlT + (long)(o0 + o) * 64 + kc * 16);
            const float4* wr4 = (const float4*)(wrT + (long)(o0 + o) * 64 + kc * 16);
            float a = 0.f;
#pragma unroll
            for (int q = 0; q < 4; q++) {
                float4 wl = wl4[q], wr = wr4[q];
                a += ar[4*q]*wl.x + ar[4*q+1]*wl.y + ar[4*q+2]*wl.z + ar[4*q+3]*wl.w
                   + xr[4*q]*wr.x + xr[4*q+1]*wr.y + xr[4*q+2]*wr.z + xr[4*q+3]*wr.w;
            }
            acc[o] += a;
        }
    }
    __syncthreads();                       // done reading sx/sa; re-use LDS
    float* hout = smem;                    // 128*65 = 8320 floats <= 8704
#pragma unroll
    for (int o = 0; o < 32; o++) hout[(o0 + o) * 65 + lane] = fmaxf(acc[o], 0.f);
    __syncthreads();
    long gbase = (long)blockIdx.x * 64 * 128;
    long gmax  = (long)N_NODES * 128;
#pragma unroll
    for (int it = 0; it < 32; it++) {
        int i = it * 256 + t;
        int n = i >> 7, c = i & 127;
        long g = gbase + i;
        if (g < gmax) h[g] = hout[c * 65 + n];
    }
}

// t2 = h@Wl2 ; u = h@Wr2 + bl2   [128 -> 64 x2]
__global__ __launch_bounds__(256, 4) void conv2t(
        const float* __restrict__ h, const float* __restrict__ wlT,
        const float* __restrict__ wrT, const float* __restrict__ bl,
        float* __restrict__ t2, float* __restrict__ u) {
    __shared__ float smem[64 * 132];       // h-tile 33.8KB; aliased by tout+uout (2*64*65)
    int t = threadIdx.x;
    int lane = t & 63;
    int o0 = __builtin_amdgcn_readfirstlane((t >> 6) * 16);

    long base = (long)blockIdx.x * 64 * 128;
    long maxe = (long)N_NODES * 128 - 4;
#pragma unroll
    for (int it = 0; it < 8; it++) {
        int f4 = it * 256 + t;                    // 0..2047
        int n = f4 >> 5, k4 = (f4 & 31) * 4;
        long g = base + (long)f4 * 4;
        if (g > maxe) g = maxe;
        float4 v = *(const float4*)(h + g);
        *(float4*)(smem + n * 132 + k4) = v;
    }
    __syncthreads();

    float accL[16], accR[16];
#pragma unroll
    for (int o = 0; o < 16; o++) { accL[o] = 0.f; accR[o] = bl[o0 + o]; }
    const float* hrow = smem + lane * 132;
#pragma unroll
    for (int kc = 0; kc < 8; kc++) {
        float hr[16];
#pragma unroll
        for (int q = 0; q < 4; q++) {
            float4 v = *(const float4*)(hrow + kc * 16 + q * 4);
            hr[4*q] = v.x; hr[4*q+1] = v.y; hr[4*q+2] = v.z; hr[4*q+3] = v.w;
        }
#pragma unroll
        for (int o = 0; o < 16; o++) {
            const float4* wl4 = (const float4*)(wlT + (long)(o0 + o) * 128 + kc * 16);
            const float4* wr4 = (const float4*)(wrT + (long)(o0 + o) * 128 + kc * 16);
            float aL = 0.f, aR = 0.f;
#pragma unroll
            for (int q = 0; q < 4; q++) {
                float4 wl = wl4[q], wr = wr4[q];
                aL += hr[4*q]*wl.x + hr[4*q+1]*wl.y + hr[4*q+2]*wl.z + hr[4*q+3]*wl.w;
                aR += hr[4*q]*wr.x + hr[4*q+1]*wr.y + hr[4*q+2]*wr.z + hr[4*q+3]*wr.w;
            }
            accL[o] += aL; accR[o] += aR;
        }
    }
    __syncthreads();
    float* tout = smem;                    // 64*65
    float* uout = smem + 64 * 65;          // 64*65 ; total 8320 <= 8448
#pragma unroll
    for (int o = 0; o < 16; o++) {
        tout[(o0 + o) * 65 + lane] = accL[o];
        uout[(o0 + o) * 65 + lane] = accR[o];
    }
    __syncthreads();
    long gbase = (long)blockIdx.x * 64 * 64;
    long gmax  = (long)N_NODES * 64;
#pragma unroll
    for (int it = 0; it < 16; it++) {
        int i = it * 256 + t;
        int n = i >> 6, c = i & 63;
        long g = gbase + i;
        if (g < gmax) {
            t2[g] = tout[c * 65 + n];
            u[g]  = uout[c * 65 + n];
        }
    }
}

// c1 = relu(emb@Wc1 + bc1)  [64 -> 128]
__global__ __launch_bounds__(256, 4) void cls1(
        const float* __restrict__ emb, const float* __restrict__ wT,
        const float* __restrict__ b, float* __restrict__ c1) {
    __shared__ float smem[128 * 65];       // 8320 floats; e-tile (64*68=4352) fits inside
    float* se = smem;
    int t = threadIdx.x;
    int lane = t & 63;
    int o0 = __builtin_amdgcn_readfirstlane((t >> 6) * 32);

    long base = (long)blockIdx.x * 64 * 64;
    long maxe = (long)N_NODES * 64 - 4;
#pragma unroll
    for (int it = 0; it < 4; it++) {
        int f4 = it * 256 + t;
        int n = f4 >> 4, k4 = (f4 & 15) * 4;
        long g = base + (long)f4 * 4;
        if (g > maxe) g = maxe;
        float4 v = *(const float4*)(emb + g);
        *(float4*)(se + n * 68 + k4) = v;
    }
    __syncthreads();

    float acc[32];
#pragma unroll
    for (int o = 0; o < 32; o++) acc[o] = b[o0 + o];
    const float* erow = se + lane * 68;
#pragma unroll
    for (int kc = 0; kc < 4; kc++) {
        float er[16];
#pragma unroll
        for (int q = 0; q < 4; q++) {
            float4 v = *(const float4*)(erow + kc * 16 + q * 4);
            er[4*q] = v.x; er[4*q+1] = v.y; er[4*q+2] = v.z; er[4*q+3] = v.w;
        }
#pragma unroll
        for (int o = 0; o < 32; o++) {
            const float4* w4 = (const float4*)(wT + (long)(o0 + o) * 64 + kc * 16);
            float a = 0.f;
#pragma unroll
            for (int q = 0; q < 4; q++) {
                float4 w = w4[q];
                a += er[4*q]*w.x + er[4*q+1]*w.y + er[4*q+2]*w.z + er[4*q+3]*w.w;
            }
            acc[o] += a;
        }
    }
    __syncthreads();
    float* cout = smem;                    // 128*65
#pragma unroll
    for (int o = 0; o < 32; o++) cout[(o0 + o) * 65 + lane] = fmaxf(acc[o], 0.f);
    __syncthreads();
    long gbase = (long)blockIdx.x * 64 * 128;
    long gmax  = (long)N_NODES * 128;
#pragma unroll
    for (int it = 0; it < 32; it++) {
        int i = it * 256 + t;
        int n = i >> 7, c = i & 127;
        long g = gbase + i;
        if (g < gmax) c1[g] = cout[c * 65 + n];
    }
}

// c2 = relu(c1@Wc2 + bc2) [128->64]; p = sigmoid(c2 . wc3 + bc3)
__global__ __launch_bounds__(256, 4) void cls2(
        const float* __restrict__ c1, const float* __restrict__ wT,
        const float* __restrict__ b2, const float* __restrict__ wc3,
        const float* __restrict__ bc3, float* __restrict__ probs) {
    __shared__ float smem[64 * 132];
    __shared__ float psum[4][64];
    int t = threadIdx.x;
    int lane = t & 63;
    int wv = t >> 6;
    int node = blockIdx.x * 64 + lane;
    int o0 = __builtin_amdgcn_readfirstlane(wv * 16);

    long base = (long)blockIdx.x * 64 * 128;
    long maxe = (long)N_NODES * 128 - 4;
#pragma unroll
    for (int it = 0; it < 8; it++) {
        int f4 = it * 256 + t;
        int n = f4 >> 5, k4 = (f4 & 31) * 4;
        long g = base + (long)f4 * 4;
        if (g > maxe) g = maxe;
        float4 v = *(const float4*)(c1 + g);
        *(float4*)(smem + n * 132 + k4) = v;
    }
    __syncthreads();

    float acc[16];
#pragma unroll
    for (int o = 0; o < 16; o++) acc[o] = b2[o0 + o];
    const float* crow = smem + lane * 132;
#pragma unroll
    for (int kc = 0; kc < 8; kc++) {
        float cr[16];
#pragma unroll
        for (int q = 0; q < 4; q++) {
            float4 v = *(const float4*)(crow + kc * 16 + q * 4);
            cr[4*q] = v.x; cr[4*q+1] = v.y; cr[4*q+2] = v.z; cr[4*q+3] = v.w;
        }
#pragma unroll
        for (int o = 0; o < 16; o++) {
            const float4* w4 = (const float4*)(wT + (long)(o0 + o) * 128 + kc * 16);
            float a = 0.f;
#pragma unroll
            for (int q = 0; q < 4; q++) {
                float4 w = w4[q];
                a += cr[4*q]*w.x + cr[4*q+1]*w.y + cr[4*q+2]*w.z + cr[4*q+3]*w.w;
            }
            acc[o] += a;
        }
    }
    float p = 0.f;
#pragma unroll
    for (int o = 0; o < 16; o++) p += fmaxf(acc[o], 0.f) * wc3[o0 + o];
    psum[wv][lane] = p;
    __syncthreads();
    if (wv == 0 && node < N_NODES) {
        float tot = psum[0][lane] + psum[1][lane] + psum[2][lane] + psum[3][lane] + bc3[0];
        probs[node] = 1.0f / (1.0f + expf(-tot));
    }
}

extern "C" void kernel_launch(void* const* d_in, const int* in_sizes, int n_in,
                              void* d_out, int out_size, void* d_ws, size_t ws_size,
                              hipStream_t stream) {
    const float* x   = (const float*)d_in[0];
    const int*   ei  = (const int*)d_in[1];
    const float* Wl1 = (const float*)d_in[2];
    const float* bl1 = (const float*)d_in[3];
    const float* Wr1 = (const float*)d_in[4];
    const float* Wl2 = (const float*)d_in[5];
    const float* bl2 = (const float*)d_in[6];
    const float* Wr2 = (const float*)d_in[7];
    const float* Wc1 = (const float*)d_in[8];
    const float* bc1 = (const float*)d_in[9];
    const float* Wc2 = (const float*)d_in[10];
    const float* bc2 = (const float*)d_in[11];
    const float* Wc3 = (const float*)d_in[12];
    const float* bc3 = (const float*)d_in[13];

    float* out = (float*)d_out;

    int* iw         = (int*)d_ws;
    int* deg_cursor = iw;                 // NPAD
    int* off        = iw + NPAD;          // NPAD
    int* bsum       = iw + 2 * NPAD;      // 128
    int* bpre       = iw + 2 * NPAD + 128;
    int* bucket     = iw + 2 * NPAD + 256;  // N_EDGES

    float* fw    = (float*)d_ws + (2 * NPAD + 256 + N_EDGES);
    float* agg1m = fw;                    // 6.4M (reused as u)
    float* u     = fw;
    float* t2    = fw + 6400000L;         // 6.4M
    float* h     = fw + 12800000L;        // 12.8M (reused as c1)
    float* c1    = h;
    float* wts   = fw + 25600000L;        // 6*8192
    float* wl1T = wts;          float* wr1T = wts + 8192;
    float* wl2T = wts + 16384;  float* wr2T = wts + 24576;
    float* wc1T = wts + 32768;  float* wc2T = wts + 40960;

    float* emb   = out;                   // [100000 x 64]
    float* probs = out + 6400000L;        // [100000]

    const int* esrc = ei;
    const int* edst = ei + N_EDGES;

    hipMemsetAsync(deg_cursor, 0, NPAD * sizeof(int), stream);

    transpose_w<<<32, 256, 0, stream>>>(Wl1, wl1T, 64, 128);
    transpose_w<<<32, 256, 0, stream>>>(Wr1, wr1T, 64, 128);
    transpose_w<<<32, 256, 0, stream>>>(Wl2, wl2T, 128, 64);
    transpose_w<<<32, 256, 0, stream>>>(Wr2, wr2T, 128, 64);
    transpose_w<<<32, 256, 0, stream>>>(Wc1, wc1T, 64, 128);
    transpose_w<<<32, 256, 0, stream>>>(Wc2, wc2T, 128, 64);

    hist_kernel<<<6250, 256, 0, stream>>>(edst, deg_cursor);
    scan_block<<<98, 1024, 0, stream>>>(deg_cursor, off, bsum);
    scan_tops<<<1, 64, 0, stream>>>(bsum, bpre);
    scan_add<<<98, 1024, 0, stream>>>(off, deg_cursor, bpre);
    scatter_kernel<<<6250, 256, 0, stream>>>(esrc, edst, deg_cursor, bucket);

    gather_mean64<<<25000, 256, 0, stream>>>(x, off, bucket, nullptr, agg1m);
    dense1<<<1563, 256, 0, stream>>>(x, agg1m, wl1T, wr1T, bl1, h);
    conv2t<<<1563, 256, 0, stream>>>(h, wl2T, wr2T, bl2, t2, u);
    gather_mean64<<<25000, 256, 0, stream>>>(t2, off, bucket, u, emb);
    cls1<<<1563, 256, 0, stream>>>(emb, wc1T, bc1, c1);
    cls2<<<1563, 256, 0, stream>>>(c1, wc2T, bc2, Wc3, bc3, probs);
}

// Round 5
// 740.348 us; speedup vs baseline: 3.1373x; 1.2021x over previous
//
#include <hip/hip_runtime.h>
#include <math.h>

#define N_NODES 100000
#define N_EDGES 1600000
#define NPAD    100352          // nodes padded to 98*1024

// all 6 weight transposes in one launch; dst[o*R+k] = src[k*C+o]
__global__ void transpose_all(const float* __restrict__ Wl1, const float* __restrict__ Wr1,
                              const float* __restrict__ Wl2, const float* __restrict__ Wr2,
                              const float* __restrict__ Wc1, const float* __restrict__ Wc2,
                              float* __restrict__ wts) {
    int i = blockIdx.x * 256 + threadIdx.x;      // 192*256 = 49152 = 6*8192
    int seg = i >> 13, j = i & 8191;
    const float* src; float* dst; int R, C;
    switch (seg) {
        case 0:  src = Wl1; dst = wts;          R = 64;  C = 128; break;
        case 1:  src = Wr1; dst = wts + 8192;   R = 64;  C = 128; break;
        case 2:  src = Wl2; dst = wts + 16384;  R = 128; C = 64;  break;
        case 3:  src = Wr2; dst = wts + 24576;  R = 128; C = 64;  break;
        case 4:  src = Wc1; dst = wts + 32768;  R = 64;  C = 128; break;
        default: src = Wc2; dst = wts + 40960;  R = 128; C = 64;  break;
    }
    int k = j / C, o = j % C;
    dst[o * R + k] = src[j];
}

__global__ void hist_kernel(const int* __restrict__ edst, int* __restrict__ deg) {
    int e = blockIdx.x * 256 + threadIdx.x;   // grid exact: 6250*256 = 1.6M
    atomicAdd(&deg[edst[e]], 1);
}

__global__ void scan_block(const int* __restrict__ deg, int* __restrict__ off,
                           int* __restrict__ bsum) {
    __shared__ int s[1024];
    int t = threadIdx.x;
    int i = blockIdx.x * 1024 + t;
    int v = deg[i];
    s[t] = v;
    __syncthreads();
    for (int st = 1; st < 1024; st <<= 1) {
        int a = (t >= st) ? s[t - st] : 0;
        __syncthreads();
        s[t] += a;
        __syncthreads();
    }
    off[i] = s[t] - v;
    if (t == 1023) bsum[blockIdx.x] = s[t];
}

__global__ void scan_tops(const int* __restrict__ bsum, int* __restrict__ bpre) {
    if (threadIdx.x == 0) {
        int r = 0;
        for (int b = 0; b < 98; b++) { bpre[b] = r; r += bsum[b]; }
    }
}

__global__ void scan_add(int* __restrict__ off, int* __restrict__ cursor,
                         const int* __restrict__ bpre) {
    int i = blockIdx.x * 1024 + threadIdx.x;
    int v = off[i] + bpre[blockIdx.x];
    off[i] = v;
    cursor[i] = v;
}

__global__ void scatter_kernel(const int* __restrict__ esrc, const int* __restrict__ edst,
                               int* __restrict__ cursor, int* __restrict__ bucket) {
    int e = blockIdx.x * 256 + threadIdx.x;
    int d = edst[e];
    int slot = atomicAdd(&cursor[d], 1);
    bucket[slot] = esrc[e];
}

// one wave per node; lane = channel (64). out = mean(y[src]) (+ add)
// unroll-4: 4 independent accumulators keep 4 cache loads in flight
__global__ void gather_mean64(const float* __restrict__ y, const int* __restrict__ off,
                              const int* __restrict__ bucket, const float* __restrict__ add,
                              float* __restrict__ out) {
    int node = __builtin_amdgcn_readfirstlane(blockIdx.x * 4 + (threadIdx.x >> 6));
    if (node >= N_NODES) return;
    int c = threadIdx.x & 63;
    int e0 = off[node], e1 = off[node + 1];
    float a0 = 0.f, a1 = 0.f, a2 = 0.f, a3 = 0.f;
    int e = e0;
    for (; e + 4 <= e1; e += 4) {
        int s0 = bucket[e], s1 = bucket[e + 1], s2 = bucket[e + 2], s3 = bucket[e + 3];
        a0 += y[(long)s0 * 64 + c];
        a1 += y[(long)s1 * 64 + c];
        a2 += y[(long)s2 * 64 + c];
        a3 += y[(long)s3 * 64 + c];
    }
    for (; e < e1; e++) a0 += y[(long)bucket[e] * 64 + c];
    float sc = 1.0f / fmaxf((float)(e1 - e0), 1.0f);
    float r = ((a0 + a1) + (a2 + a3)) * sc;
    if (add) r += add[(long)node * 64 + c];
    out[(long)node * 64 + c] = r;
}

// fused conv1 + conv2-transform:
//   h   = relu(agg@Wl1 + bl1 + x@Wr1)      (stays in LDS)
//   t2  = h@Wl2 ; u = h@Wr2 + bl2
__global__ __launch_bounds__(256, 4) void fused_conv(
        const float* __restrict__ x, const float* __restrict__ agg,
        const float* __restrict__ wl1T, const float* __restrict__ wr1T,
        const float* __restrict__ bl1,
        const float* __restrict__ wl2T, const float* __restrict__ wr2T,
        const float* __restrict__ bl2,
        float* __restrict__ t2, float* __restrict__ u) {
    __shared__ float smem[8704];           // 34.8 KB, aliased across phases
    float* sx = smem;                      // 64*68
    float* sa = smem + 4352;               // 64*68
    int t = threadIdx.x;
    int lane = t & 63;
    int wv = t >> 6;

    long base = (long)blockIdx.x * 4096;
    long maxe = (long)N_NODES * 64 - 4;
#pragma unroll
    for (int it = 0; it < 4; it++) {
        int f4 = it * 256 + t;
        int n = f4 >> 4, k4 = (f4 & 15) * 4;
        long g = base + (long)f4 * 4;
        if (g > maxe) g = maxe;
        *(float4*)(sx + n * 68 + k4) = *(const float4*)(x + g);
        *(float4*)(sa + n * 68 + k4) = *(const float4*)(agg + g);
    }
    __syncthreads();

    // ---- conv1: h channels [o0, o0+32) for this lane's node ----
    int o0 = __builtin_amdgcn_readfirstlane(wv * 32);
    float acc[32];
#pragma unroll
    for (int o = 0; o < 32; o++) acc[o] = bl1[o0 + o];
    {
        const float* xrow = sx + lane * 68;
        const float* arow = sa + lane * 68;
#pragma unroll
        for (int kc = 0; kc < 4; kc++) {
            float xr[16], ar[16];
#pragma unroll
            for (int q = 0; q < 4; q++) {
                float4 v = *(const float4*)(xrow + kc * 16 + q * 4);
                xr[4*q] = v.x; xr[4*q+1] = v.y; xr[4*q+2] = v.z; xr[4*q+3] = v.w;
                float4 a = *(const float4*)(arow + kc * 16 + q * 4);
                ar[4*q] = a.x; ar[4*q+1] = a.y; ar[4*q+2] = a.z; ar[4*q+3] = a.w;
            }
#pragma unroll
            for (int o = 0; o < 32; o++) {
                const float4* wl4 = (const float4*)(wl1T + (long)(o0 + o) * 64 + kc * 16);
                const float4* wr4 = (const float4*)(wr1T + (long)(o0 + o) * 64 + kc * 16);
                float s = 0.f;
#pragma unroll
                for (int q = 0; q < 4; q++) {
                    float4 wl = wl4[q], wr = wr4[q];
                    s += ar[4*q]*wl.x + ar[4*q+1]*wl.y + ar[4*q+2]*wl.z + ar[4*q+3]*wl.w
                       + xr[4*q]*wr.x + xr[4*q+1]*wr.y + xr[4*q+2]*wr.z + xr[4*q+3]*wr.w;
                }
                acc[o] += s;
            }
        }
    }
    __syncthreads();                       // done with sx/sa
    float* hs = smem;                      // h staged col-major [128][65]
#pragma unroll
    for (int o = 0; o < 32; o++) hs[(o0 + o) * 65 + lane] = fmaxf(acc[o], 0.f);
    __syncthreads();

    // ---- conv2 transform: t2/u channels [o1, o1+16) ----
    int o1 = __builtin_amdgcn_readfirstlane(wv * 16);
    float accL[16], accR[16];
#pragma unroll
    for (int o = 0; o < 16; o++) { accL[o] = 0.f; accR[o] = bl2[o1 + o]; }
#pragma unroll
    for (int kc = 0; kc < 8; kc++) {
        float hr[16];
#pragma unroll
        for (int q = 0; q < 16; q++) hr[q] = hs[(kc * 16 + q) * 65 + lane];
#pragma unroll
        for (int o = 0; o < 16; o++) {
            const float4* wl4 = (const float4*)(wl2T + (long)(o1 + o) * 128 + kc * 16);
            const float4* wr4 = (const float4*)(wr2T + (long)(o1 + o) * 128 + kc * 16);
            float aL = 0.f, aR = 0.f;
#pragma unroll
            for (int q = 0; q < 4; q++) {
                float4 wl = wl4[q], wr = wr4[q];
                aL += hr[4*q]*wl.x + hr[4*q+1]*wl.y + hr[4*q+2]*wl.z + hr[4*q+3]*wl.w;
                aR += hr[4*q]*wr.x + hr[4*q+1]*wr.y + hr[4*q+2]*wr.z + hr[4*q+3]*wr.w;
            }
            accL[o] += aL; accR[o] += aR;
        }
    }
    __syncthreads();                       // done reading hs
    float* tout = smem;                    // 64*65
    float* uout = smem + 4160;             // 64*65, total 8320 <= 8704
#pragma unroll
    for (int o = 0; o < 16; o++) {
        tout[(o1 + o) * 65 + lane] = accL[o];
        uout[(o1 + o) * 65 + lane] = accR[o];
    }
    __syncthreads();
    long gmax = (long)N_NODES * 64;
#pragma unroll
    for (int it = 0; it < 16; it++) {
        int i = it * 256 + t;
        int n = i >> 6, c = i & 63;
        long g = base + i;
        if (g < gmax) {
            t2[g] = tout[c * 65 + n];
            u[g]  = uout[c * 65 + n];
        }
    }
}

// fused classifier head: c1 = relu(emb@Wc1+bc1) (LDS only);
// c2 = relu(c1@Wc2+bc2); p = sigmoid(c2.wc3 + bc3)
__global__ __launch_bounds__(256, 4) void fused_cls(
        const float* __restrict__ emb,
        const float* __restrict__ wc1T, const float* __restrict__ bc1,
        const float* __restrict__ wc2T, const float* __restrict__ bc2,
        const float* __restrict__ wc3, const float* __restrict__ bc3,
        float* __restrict__ probs) {
    __shared__ float smem[8320];
    __shared__ float psum[4][64];
    int t = threadIdx.x;
    int lane = t & 63;
    int wv = t >> 6;
    int node = blockIdx.x * 64 + lane;

    float* se = smem;                      // 64*68
    long base = (long)blockIdx.x * 4096;
    long maxe = (long)N_NODES * 64 - 4;
#pragma unroll
    for (int it = 0; it < 4; it++) {
        int f4 = it * 256 + t;
        int n = f4 >> 4, k4 = (f4 & 15) * 4;
        long g = base + (long)f4 * 4;
        if (g > maxe) g = maxe;
        *(float4*)(se + n * 68 + k4) = *(const float4*)(emb + g);
    }
    __syncthreads();

    int o0 = __builtin_amdgcn_readfirstlane(wv * 32);
    float acc[32];
#pragma unroll
    for (int o = 0; o < 32; o++) acc[o] = bc1[o0 + o];
    {
        const float* erow = se + lane * 68;
#pragma unroll
        for (int kc = 0; kc < 4; kc++) {
            float er[16];
#pragma unroll
            for (int q = 0; q < 4; q++) {
                float4 v = *(const float4*)(erow + kc * 16 + q * 4);
                er[4*q] = v.x; er[4*q+1] = v.y; er[4*q+2] = v.z; er[4*q+3] = v.w;
            }
#pragma unroll
            for (int o = 0; o < 32; o++) {
                const float4* w4 = (const float4*)(wc1T + (long)(o0 + o) * 64 + kc * 16);
                float s = 0.f;
#pragma unroll
                for (int q = 0; q < 4; q++) {
                    float4 w = w4[q];
                    s += er[4*q]*w.x + er[4*q+1]*w.y + er[4*q+2]*w.z + er[4*q+3]*w.w;
                }
                acc[o] += s;
            }
        }
    }
    __syncthreads();                       // done with se
    float* c1s = smem;                     // [128][65]
#pragma unroll
    for (int o = 0; o < 32; o++) c1s[(o0 + o) * 65 + lane] = fmaxf(acc[o], 0.f);
    __syncthreads();

    int o1 = __builtin_amdgcn_readfirstlane(wv * 16);
    float a2[16];
#pragma unroll
    for (int o = 0; o < 16; o++) a2[o] = bc2[o1 + o];
#pragma unroll
    for (int kc = 0; kc < 8; kc++) {
        float cr[16];
#pragma unroll
        for (int q = 0; q < 16; q++) cr[q] = c1s[(kc * 16 + q) * 65 + lane];
#pragma unroll
        for (int o = 0; o < 16; o++) {
            const float4* w4 = (const float4*)(wc2T + (long)(o1 + o) * 128 + kc * 16);
            float s = 0.f;
#pragma unroll
            for (int q = 0; q < 4; q++) {
                float4 w = w4[q];
                s += cr[4*q]*w.x + cr[4*q+1]*w.y + cr[4*q+2]*w.z + cr[4*q+3]*w.w;
            }
            a2[o] += s;
        }
    }
    float p = 0.f;
#pragma unroll
    for (int o = 0; o < 16; o++) p += fmaxf(a2[o], 0.f) * wc3[o1 + o];
    psum[wv][lane] = p;
    __syncthreads();
    if (wv == 0 && node < N_NODES) {
        float tot = psum[0][lane] + psum[1][lane] + psum[2][lane] + psum[3][lane] + bc3[0];
        probs[node] = 1.0f / (1.0f + expf(-tot));
    }
}

extern "C" void kernel_launch(void* const* d_in, const int* in_sizes, int n_in,
                              void* d_out, int out_size, void* d_ws, size_t ws_size,
                              hipStream_t stream) {
    const float* x   = (const float*)d_in[0];
    const int*   ei  = (const int*)d_in[1];
    const float* Wl1 = (const float*)d_in[2];
    const float* bl1 = (const float*)d_in[3];
    const float* Wr1 = (const float*)d_in[4];
    const float* Wl2 = (const float*)d_in[5];
    const float* bl2 = (const float*)d_in[6];
    const float* Wr2 = (const float*)d_in[7];
    const float* Wc1 = (const float*)d_in[8];
    const float* bc1 = (const float*)d_in[9];
    const float* Wc2 = (const float*)d_in[10];
    const float* bc2 = (const float*)d_in[11];
    const float* Wc3 = (const float*)d_in[12];
    const float* bc3 = (const float*)d_in[13];

    float* out = (float*)d_out;

    int* iw         = (int*)d_ws;
    int* deg_cursor = iw;                   // NPAD
    int* off        = iw + NPAD;            // NPAD
    int* bsum       = iw + 2 * NPAD;        // 128
    int* bpre       = iw + 2 * NPAD + 128;  // 128
    int* bucket     = iw + 2 * NPAD + 256;  // N_EDGES

    float* fw    = (float*)d_ws + (2 * NPAD + 256 + N_EDGES);
    float* agg1m = fw;                      // 6.4M
    float* t2    = fw + 6400000L;           // 6.4M
    float* u     = fw + 12800000L;          // 6.4M
    float* wts   = fw + 19200000L;          // 6*8192
    float* wl1T = wts;          float* wr1T = wts + 8192;
    float* wl2T = wts + 16384;  float* wr2T = wts + 24576;
    float* wc1T = wts + 32768;  float* wc2T = wts + 40960;

    float* emb   = out;                     // [100000 x 64]
    float* probs = out + 6400000L;          // [100000]

    const int* esrc = ei;
    const int* edst = ei + N_EDGES;

    hipMemsetAsync(deg_cursor, 0, NPAD * sizeof(int), stream);

    transpose_all<<<192, 256, 0, stream>>>(Wl1, Wr1, Wl2, Wr2, Wc1, Wc2, wts);

    hist_kernel<<<6250, 256, 0, stream>>>(edst, deg_cursor);
    scan_block<<<98, 1024, 0, stream>>>(deg_cursor, off, bsum);
    scan_tops<<<1, 64, 0, stream>>>(bsum, bpre);
    scan_add<<<98, 1024, 0, stream>>>(off, deg_cursor, bpre);
    scatter_kernel<<<6250, 256, 0, stream>>>(esrc, edst, deg_cursor, bucket);

    gather_mean64<<<25000, 256, 0, stream>>>(x, off, bucket, nullptr, agg1m);
    fused_conv<<<1563, 256, 0, stream>>>(x, agg1m, wl1T, wr1T, bl1,
                                         wl2T, wr2T, bl2, t2, u);
    gather_mean64<<<25000, 256, 0, stream>>>(t2, off, bucket, u, emb);
    fused_cls<<<1563, 256, 0, stream>>>(emb, wc1T, bc1, wc2T, bc2, Wc3, bc3, probs);
}

// Round 6
// 433.699 us; speedup vs baseline: 5.3555x; 1.7071x over previous
//
#include <hip/hip_runtime.h>
#include <math.h>

#define N_NODES 100000
#define N_EDGES 1600000
#define NPAD    100352          // nodes padded to 98*1024

using short8  = __attribute__((ext_vector_type(8))) short;   // 8 bf16 (4 VGPRs)
using float4v = __attribute__((ext_vector_type(4))) float;   // MFMA C/D frag

__device__ inline unsigned short f2bf(float f) {             // fp32 -> bf16 RNE
    unsigned int u = __float_as_uint(f);
    u += 0x7fffu + ((u >> 16) & 1u);
    return (unsigned short)(u >> 16);
}
__device__ inline float bflo(unsigned int v) { return __uint_as_float(v << 16); }
__device__ inline float bfhi(unsigned int v) { return __uint_as_float(v & 0xffff0000u); }

// ---- weight prep: transpose to [n][k] bf16, conv mats concatenated ----
// w1[n=128][k=128]: k<64 -> Wl1[k][n] (agg path), k>=64 -> Wr1[k-64][n] (x path)
// w2[n=128][k=128]: n<64 -> Wl2[k][n] (t2 cols),  n>=64 -> Wr2[k][n-64] (u cols)
// wcls1[n=128][k=64]: Wc1[k][n] ; wcls2[n=64][k=128]: Wc2[k][n]
__global__ void prep_weights(const float* __restrict__ Wl1, const float* __restrict__ Wr1,
                             const float* __restrict__ Wl2, const float* __restrict__ Wr2,
                             const float* __restrict__ Wc1, const float* __restrict__ Wc2,
                             unsigned short* __restrict__ w1, unsigned short* __restrict__ w2,
                             unsigned short* __restrict__ wcls1, unsigned short* __restrict__ wcls2) {
    int i = blockIdx.x * 256 + threadIdx.x;          // 192*256 = 49152
    if (i < 16384) {
        int n = i >> 7, k = i & 127;
        float v = (k < 64) ? Wl1[k * 128 + n] : Wr1[(k - 64) * 128 + n];
        w1[i] = f2bf(v);
    } else if (i < 32768) {
        int j = i - 16384; int n = j >> 7, k = j & 127;
        float v = (n < 64) ? Wl2[k * 64 + n] : Wr2[k * 64 + (n - 64)];
        w2[j] = f2bf(v);
    } else if (i < 40960) {
        int j = i - 32768; int n = j >> 6, k = j & 63;
        wcls1[j] = f2bf(Wc1[k * 128 + n]);
    } else {
        int j = i - 40960; int n = j >> 7, k = j & 127;
        wcls2[j] = f2bf(Wc2[k * 64 + n]);
    }
}

// x fp32 -> bf16, 4 elems/thread
__global__ void f32_to_bf16x4(const float* __restrict__ src, unsigned short* __restrict__ dst) {
    int i = blockIdx.x * 256 + threadIdx.x;          // 6250*256*4 = 6.4M
    float4 v = *(const float4*)(src + (long)i * 4);
    uint2 o;
    o.x = (unsigned)f2bf(v.x) | ((unsigned)f2bf(v.y) << 16);
    o.y = (unsigned)f2bf(v.z) | ((unsigned)f2bf(v.w) << 16);
    *(uint2*)(dst + (long)i * 4) = o;
}

// ---- CSR build ----
__global__ void hist_kernel(const int* __restrict__ edst, int* __restrict__ deg) {
    int e = blockIdx.x * 256 + threadIdx.x;
    atomicAdd(&deg[edst[e]], 1);
}

__global__ void scan_block(const int* __restrict__ deg, int* __restrict__ off,
                           int* __restrict__ bsum) {
    __shared__ int s[1024];
    int t = threadIdx.x;
    int i = blockIdx.x * 1024 + t;
    int v = deg[i];
    s[t] = v;
    __syncthreads();
    for (int st = 1; st < 1024; st <<= 1) {
        int a = (t >= st) ? s[t - st] : 0;
        __syncthreads();
        s[t] += a;
        __syncthreads();
    }
    off[i] = s[t] - v;
    if (t == 1023) bsum[blockIdx.x] = s[t];
}

__global__ void scan_tops(const int* __restrict__ bsum, int* __restrict__ bpre) {
    if (threadIdx.x == 0) {
        int r = 0;
        for (int b = 0; b < 98; b++) { bpre[b] = r; r += bsum[b]; }
    }
}

__global__ void scan_add(int* __restrict__ off, int* __restrict__ cursor,
                         const int* __restrict__ bpre) {
    int i = blockIdx.x * 1024 + threadIdx.x;
    int v = off[i] + bpre[blockIdx.x];
    off[i] = v;
    cursor[i] = v;
}

__global__ void scatter_kernel(const int* __restrict__ esrc, const int* __restrict__ edst,
                               int* __restrict__ cursor, int* __restrict__ bucket) {
    int e = blockIdx.x * 256 + threadIdx.x;
    int d = edst[e];
    int slot = atomicAdd(&cursor[d], 1);
    bucket[slot] = esrc[e];
}

// ---- bf16 gather: wave per node; lane = (neighbor g = lane>>3, channel octet c8) ----
__global__ __launch_bounds__(256, 8) void gather_b(
        const unsigned short* __restrict__ y, const int* __restrict__ off,
        const int* __restrict__ bucket, unsigned short* __restrict__ outb) {
    int node = __builtin_amdgcn_readfirstlane(blockIdx.x * 4 + (threadIdx.x >> 6));
    int lane = threadIdx.x & 63;
    int g = lane >> 3, c8 = lane & 7;
    int e0 = off[node], e1 = off[node + 1];
    float a[8] = {0.f, 0.f, 0.f, 0.f, 0.f, 0.f, 0.f, 0.f};
    for (int base = e0; base < e1; base += 8) {
        int idx = base + g;
        if (idx < e1) {
            int s = bucket[idx];
            uint4 v = *(const uint4*)(y + (long)s * 64 + c8 * 8);
            a[0] += bflo(v.x); a[1] += bfhi(v.x);
            a[2] += bflo(v.y); a[3] += bfhi(v.y);
            a[4] += bflo(v.z); a[5] += bfhi(v.z);
            a[6] += bflo(v.w); a[7] += bfhi(v.w);
        }
    }
#pragma unroll
    for (int j = 0; j < 8; j++) {
        a[j] += __shfl_xor(a[j], 8);
        a[j] += __shfl_xor(a[j], 16);
        a[j] += __shfl_xor(a[j], 32);
    }
    if (g == 0) {
        float sc = 1.f / fmaxf((float)(e1 - e0), 1.f);
        uint4 o;
        o.x = (unsigned)f2bf(a[0]*sc) | ((unsigned)f2bf(a[1]*sc) << 16);
        o.y = (unsigned)f2bf(a[2]*sc) | ((unsigned)f2bf(a[3]*sc) << 16);
        o.z = (unsigned)f2bf(a[4]*sc) | ((unsigned)f2bf(a[5]*sc) << 16);
        o.w = (unsigned)f2bf(a[6]*sc) | ((unsigned)f2bf(a[7]*sc) << 16);
        *(uint4*)(outb + (long)node * 64 + c8 * 8) = o;
    }
}

// same, + fp32 add-term, fp32 output (emb)
__global__ __launch_bounds__(256, 8) void gather_badd(
        const unsigned short* __restrict__ y, const int* __restrict__ off,
        const int* __restrict__ bucket, const float* __restrict__ add,
        float* __restrict__ out) {
    int node = __builtin_amdgcn_readfirstlane(blockIdx.x * 4 + (threadIdx.x >> 6));
    int lane = threadIdx.x & 63;
    int g = lane >> 3, c8 = lane & 7;
    int e0 = off[node], e1 = off[node + 1];
    float a[8] = {0.f, 0.f, 0.f, 0.f, 0.f, 0.f, 0.f, 0.f};
    for (int base = e0; base < e1; base += 8) {
        int idx = base + g;
        if (idx < e1) {
            int s = bucket[idx];
            uint4 v = *(const uint4*)(y + (long)s * 64 + c8 * 8);
            a[0] += bflo(v.x); a[1] += bfhi(v.x);
            a[2] += bflo(v.y); a[3] += bfhi(v.y);
            a[4] += bflo(v.z); a[5] += bfhi(v.z);
            a[6] += bflo(v.w); a[7] += bfhi(v.w);
        }
    }
#pragma unroll
    for (int j = 0; j < 8; j++) {
        a[j] += __shfl_xor(a[j], 8);
        a[j] += __shfl_xor(a[j], 16);
        a[j] += __shfl_xor(a[j], 32);
    }
    if (g == 0) {
        float sc = 1.f / fmaxf((float)(e1 - e0), 1.f);
        const float4* up = (const float4*)(add + (long)node * 64 + c8 * 8);
        float4 u0 = up[0], u1 = up[1];
        float4 r0 = { a[0]*sc + u0.x, a[1]*sc + u0.y, a[2]*sc + u0.z, a[3]*sc + u0.w };
        float4 r1 = { a[4]*sc + u1.x, a[5]*sc + u1.y, a[6]*sc + u1.z, a[7]*sc + u1.w };
        float4* op = (float4*)(out + (long)node * 64 + c8 * 8);
        op[0] = r0; op[1] = r1;
    }
}

// ---- fused conv1 + conv2-transform, bf16 MFMA ----
// GEMM1: [agg|x] (64x128) @ w1^T -> h (64x128), relu, stays in LDS
// GEMM2: h @ w2^T -> [t2|u] (64x128); t2 bf16, u fp32 (+bl2)
__global__ __launch_bounds__(256, 4) void fused_conv(
        const unsigned short* __restrict__ xb, const unsigned short* __restrict__ aggb,
        const unsigned short* __restrict__ w1, const float* __restrict__ bl1,
        const unsigned short* __restrict__ w2, const float* __restrict__ bl2,
        unsigned short* __restrict__ t2b, float* __restrict__ u) {
    __shared__ __align__(16) unsigned short smemA[64 * 136];   // 17408 B
    __shared__ __align__(16) unsigned short smemH[64 * 136];   // 17408 B
    unsigned short* sA = smemA;
    unsigned short* sH = smemH;
    float* su = (float*)smemA;                 // alias: u-stage [64][68] fp32
    unsigned short* st2 = smemH;               // alias: t2-stage [64][72] bf16

    int t = threadIdx.x;
    int lane = t & 63;
    int wv = t >> 6;
    int q = lane >> 4, ln = lane & 15;

    long base = (long)blockIdx.x * 4096;
    long maxe = (long)N_NODES * 64 - 8;
#pragma unroll
    for (int it = 0; it < 2; it++) {
        int i = it * 256 + t;                  // 512 groups of 8 bf16
        int m = i >> 3, k8 = (i & 7) * 8;
        long g = base + (long)m * 64 + k8;
        if (g > maxe) g = maxe;
        *(uint4*)(sA + m * 136 + k8)      = *(const uint4*)(aggb + g);
        *(uint4*)(sA + m * 136 + 64 + k8) = *(const uint4*)(xb + g);
    }
    __syncthreads();

    // ---- GEMM1: K=128, wave covers n in [wv*32, wv*32+32) ----
    int n0 = wv * 32;
    float4v acc[2][4];
    {
        float b0 = bl1[n0 + ln], b1 = bl1[n0 + 16 + ln];
#pragma unroll
        for (int mi = 0; mi < 4; mi++) {
            acc[0][mi] = (float4v){b0, b0, b0, b0};
            acc[1][mi] = (float4v){b1, b1, b1, b1};
        }
    }
#pragma unroll
    for (int ks = 0; ks < 4; ks++) {
        int k0 = ks * 32 + q * 8;
        short8 bf0 = *(const short8*)(w1 + (long)(n0 + ln) * 128 + k0);
        short8 bf1 = *(const short8*)(w1 + (long)(n0 + 16 + ln) * 128 + k0);
#pragma unroll
        for (int mi = 0; mi < 4; mi++) {
            short8 af = *(const short8*)(sA + (mi * 16 + ln) * 136 + k0);
            acc[0][mi] = __builtin_amdgcn_mfma_f32_16x16x32_bf16(af, bf0, acc[0][mi], 0, 0, 0);
            acc[1][mi] = __builtin_amdgcn_mfma_f32_16x16x32_bf16(af, bf1, acc[1][mi], 0, 0, 0);
        }
    }
    // h = relu(.) -> sH  (C/D: col=ln, row=q*4+reg)
#pragma unroll
    for (int j = 0; j < 2; j++)
#pragma unroll
        for (int mi = 0; mi < 4; mi++) {
            int n = n0 + j * 16 + ln;
#pragma unroll
            for (int r = 0; r < 4; r++) {
                int m = mi * 16 + q * 4 + r;
                sH[m * 136 + n] = f2bf(fmaxf(acc[j][mi][r], 0.f));
            }
        }
    __syncthreads();

    // ---- GEMM2: K=128 over h; waves 0,1 -> t2 (n 0..63), waves 2,3 -> u ----
    float4v acc2[2][4];
    {
        float c0 = (n0 >= 64) ? bl2[n0 - 64 + ln] : 0.f;
        float c1 = (n0 >= 64) ? bl2[n0 - 48 + ln] : 0.f;
#pragma unroll
        for (int mi = 0; mi < 4; mi++) {
            acc2[0][mi] = (float4v){c0, c0, c0, c0};
            acc2[1][mi] = (float4v){c1, c1, c1, c1};
        }
    }
#pragma unroll
    for (int ks = 0; ks < 4; ks++) {
        int k0 = ks * 32 + q * 8;
        short8 bf0 = *(const short8*)(w2 + (long)(n0 + ln) * 128 + k0);
        short8 bf1 = *(const short8*)(w2 + (long)(n0 + 16 + ln) * 128 + k0);
#pragma unroll
        for (int mi = 0; mi < 4; mi++) {
            short8 af = *(const short8*)(sH + (mi * 16 + ln) * 136 + k0);
            acc2[0][mi] = __builtin_amdgcn_mfma_f32_16x16x32_bf16(af, bf0, acc2[0][mi], 0, 0, 0);
            acc2[1][mi] = __builtin_amdgcn_mfma_f32_16x16x32_bf16(af, bf1, acc2[1][mi], 0, 0, 0);
        }
    }
    __syncthreads();     // all reads of sA/sH done -> safe to alias su/st2

#pragma unroll
    for (int j = 0; j < 2; j++)
#pragma unroll
        for (int mi = 0; mi < 4; mi++) {
            int n = n0 + j * 16 + ln;
#pragma unroll
            for (int r = 0; r < 4; r++) {
                int m = mi * 16 + q * 4 + r;
                if (wv < 2) st2[m * 72 + n] = f2bf(acc2[j][mi][r]);
                else        su[m * 68 + (n - 64)] = acc2[j][mi][r];
            }
        }
    __syncthreads();

    long lim = (long)N_NODES * 64;
    unsigned int* t2u = (unsigned int*)(t2b + base);
#pragma unroll
    for (int it = 0; it < 8; it++) {
        int i = it * 256 + t;                  // uint index (2 bf16)
        long g = base + (long)i * 2;
        if (g + 1 < lim) {
            int m = (i * 2) >> 6, n = (i * 2) & 63;
            t2u[i] = (unsigned)st2[m * 72 + n] | ((unsigned)st2[m * 72 + n + 1] << 16);
        }
    }
#pragma unroll
    for (int it = 0; it < 16; it++) {
        int i = it * 256 + t;
        long g = base + i;
        if (g < lim) u[g] = su[(i >> 6) * 68 + (i & 63)];
    }
}

// ---- fused classifier head, bf16 MFMA ----
// c1 = relu(emb@Wc1+bc1) (K=64,N=128, LDS only); c2 = relu(c1@Wc2+bc2) (K=128,N=64);
// p = sigmoid(c2 . wc3 + bc3)
__global__ __launch_bounds__(256, 4) void fused_cls(
        const float* __restrict__ emb,
        const unsigned short* __restrict__ wcls1, const float* __restrict__ bc1,
        const unsigned short* __restrict__ wcls2, const float* __restrict__ bc2,
        const float* __restrict__ wc3, const float* __restrict__ bc3,
        float* __restrict__ probs) {
    __shared__ __align__(16) unsigned short smem[64 * 136];    // sE [64][72] aliased by sC [64][136]
    __shared__ float psum[4][64];
    unsigned short* sE = smem;
    unsigned short* sC = smem;

    int t = threadIdx.x;
    int lane = t & 63;
    int wv = t >> 6;
    int q = lane >> 4, ln = lane & 15;

    long base = (long)blockIdx.x * 4096;
    long maxe = (long)N_NODES * 64 - 4;
#pragma unroll
    for (int it = 0; it < 4; it++) {
        int i = it * 256 + t;                  // 1024 float4 groups
        int m = i >> 4, k4 = (i & 15) * 4;
        long g = base + (long)m * 64 + k4;
        if (g > maxe) g = maxe;
        float4 v = *(const float4*)(emb + g);
        uint2 o;
        o.x = (unsigned)f2bf(v.x) | ((unsigned)f2bf(v.y) << 16);
        o.y = (unsigned)f2bf(v.z) | ((unsigned)f2bf(v.w) << 16);
        *(uint2*)(sE + m * 72 + k4) = o;
    }
    __syncthreads();

    // GEMM1: K=64
    int n0 = wv * 32;
    float4v acc[2][4];
    {
        float b0 = bc1[n0 + ln], b1 = bc1[n0 + 16 + ln];
#pragma unroll
        for (int mi = 0; mi < 4; mi++) {
            acc[0][mi] = (float4v){b0, b0, b0, b0};
            acc[1][mi] = (float4v){b1, b1, b1, b1};
        }
    }
#pragma unroll
    for (int ks = 0; ks < 2; ks++) {
        int k0 = ks * 32 + q * 8;
        short8 bf0 = *(const short8*)(wcls1 + (long)(n0 + ln) * 64 + k0);
        short8 bf1 = *(const short8*)(wcls1 + (long)(n0 + 16 + ln) * 64 + k0);
#pragma unroll
        for (int mi = 0; mi < 4; mi++) {
            short8 af = *(const short8*)(sE + (mi * 16 + ln) * 72 + k0);
            acc[0][mi] = __builtin_amdgcn_mfma_f32_16x16x32_bf16(af, bf0, acc[0][mi], 0, 0, 0);
            acc[1][mi] = __builtin_amdgcn_mfma_f32_16x16x32_bf16(af, bf1, acc[1][mi], 0, 0, 0);
        }
    }
    __syncthreads();     // all sE reads done -> safe to overwrite with sC
#pragma unroll
    for (int j = 0; j < 2; j++)
#pragma unroll
        for (int mi = 0; mi < 4; mi++) {
            int n = n0 + j * 16 + ln;
#pragma unroll
            for (int r = 0; r < 4; r++) {
                int m = mi * 16 + q * 4 + r;
                sC[m * 136 + n] = f2bf(fmaxf(acc[j][mi][r], 0.f));
            }
        }
    __syncthreads();

    // GEMM2: K=128, N=64; wave wv covers n-tile [wv*16, wv*16+16)
    int n0c = wv * 16;
    float4v acc3[4];
    {
        float b = bc2[n0c + ln];
#pragma unroll
        for (int mi = 0; mi < 4; mi++) acc3[mi] = (float4v){b, b, b, b};
    }
#pragma unroll
    for (int ks = 0; ks < 4; ks++) {
        int k0 = ks * 32 + q * 8;
        short8 bf0 = *(const short8*)(wcls2 + (long)(n0c + ln) * 128 + k0);
#pragma unroll
        for (int mi = 0; mi < 4; mi++) {
            short8 af = *(const short8*)(sC + (mi * 16 + ln) * 136 + k0);
            acc3[mi] = __builtin_amdgcn_mfma_f32_16x16x32_bf16(af, bf0, acc3[mi], 0, 0, 0);
        }
    }
    float w3 = wc3[n0c + ln];
#pragma unroll
    for (int mi = 0; mi < 4; mi++)
#pragma unroll
        for (int r = 0; r < 4; r++) {
            float v = fmaxf(acc3[mi][r], 0.f) * w3;
            v += __shfl_xor(v, 1);
            v += __shfl_xor(v, 2);
            v += __shfl_xor(v, 4);
            v += __shfl_xor(v, 8);
            if (ln == 0) psum[wv][mi * 16 + q * 4 + r] = v;
        }
    __syncthreads();
    if (t < 64) {
        int node = blockIdx.x * 64 + t;
        if (node < N_NODES) {
            float tot = psum[0][t] + psum[1][t] + psum[2][t] + psum[3][t] + bc3[0];
            probs[node] = 1.f / (1.f + expf(-tot));
        }
    }
}

extern "C" void kernel_launch(void* const* d_in, const int* in_sizes, int n_in,
                              void* d_out, int out_size, void* d_ws, size_t ws_size,
                              hipStream_t stream) {
    const float* x   = (const float*)d_in[0];
    const int*   ei  = (const int*)d_in[1];
    const float* Wl1 = (const float*)d_in[2];
    const float* bl1 = (const float*)d_in[3];
    const float* Wr1 = (const float*)d_in[4];
    const float* Wl2 = (const float*)d_in[5];
    const float* bl2 = (const float*)d_in[6];
    const float* Wr2 = (const float*)d_in[7];
    const float* Wc1 = (const float*)d_in[8];
    const float* bc1 = (const float*)d_in[9];
    const float* Wc2 = (const float*)d_in[10];
    const float* bc2 = (const float*)d_in[11];
    const float* Wc3 = (const float*)d_in[12];
    const float* bc3 = (const float*)d_in[13];

    float* out = (float*)d_out;

    // ---- ws carve (bytes) ----
    int* iw         = (int*)d_ws;
    int* deg_cursor = iw;                     // NPAD
    int* off        = iw + NPAD;              // NPAD
    int* bsum       = iw + 2 * NPAD;          // 128
    int* bpre       = iw + 2 * NPAD + 128;    // 128
    int* bucket     = iw + 2 * NPAD + 256;    // N_EDGES
    size_t ioff = (size_t)(2 * NPAD + 256 + N_EDGES) * 4;   // 7203840 B

    char* wsb = (char*)d_ws;
    unsigned short* xb    = (unsigned short*)(wsb + ioff);                  // 12.8 MB
    unsigned short* agg1b = xb + 6400000L;                                  // 12.8 MB
    unsigned short* t2b   = agg1b + 6400000L;                               // 12.8 MB
    float*          u     = (float*)(wsb + ioff + 3L * 12800000L);          // 25.6 MB
    unsigned short* w1    = (unsigned short*)(wsb + ioff + 3L * 12800000L + 25600000L);
    unsigned short* w2    = w1 + 16384;
    unsigned short* wcls1 = w2 + 16384;
    unsigned short* wcls2 = wcls1 + 8192;

    float* emb   = out;                       // [100000 x 64]
    float* probs = out + 6400000L;            // [100000]

    const int* esrc = ei;
    const int* edst = ei + N_EDGES;

    hipMemsetAsync(deg_cursor, 0, NPAD * sizeof(int), stream);

    prep_weights<<<192, 256, 0, stream>>>(Wl1, Wr1, Wl2, Wr2, Wc1, Wc2,
                                          w1, w2, wcls1, wcls2);
    f32_to_bf16x4<<<6250, 256, 0, stream>>>(x, xb);

    hist_kernel<<<6250, 256, 0, stream>>>(edst, deg_cursor);
    scan_block<<<98, 1024, 0, stream>>>(deg_cursor, off, bsum);
    scan_tops<<<1, 64, 0, stream>>>(bsum, bpre);
    scan_add<<<98, 1024, 0, stream>>>(off, deg_cursor, bpre);
    scatter_kernel<<<6250, 256, 0, stream>>>(esrc, edst, deg_cursor, bucket);

    gather_b<<<25000, 256, 0, stream>>>(xb, off, bucket, agg1b);
    fused_conv<<<1563, 256, 0, stream>>>(xb, agg1b, w1, bl1, w2, bl2, t2b, u);
    gather_badd<<<25000, 256, 0, stream>>>(t2b, off, bucket, u, emb);
    fused_cls<<<1563, 256, 0, stream>>>(emb, wcls1, bc1, wcls2, bc2, Wc3, bc3, probs);
}